// Round 2
// baseline (760.864 us; speedup 1.0000x reference)
//
#include <hip/hip_runtime.h>

#define NEMB 512
#define EMB 64
#define BSTR 262144          // 64*4096
#define DECAYF 0.99f
#define OMDF 0.01f
#define EPSF 1e-5f
#define GAP_T 0.125f

typedef __attribute__((ext_vector_type(8))) short bf16x8;
typedef __attribute__((ext_vector_type(4))) float f32x4;

__device__ __forceinline__ unsigned short f2bf(float f) {
    unsigned u = __float_as_uint(f);
    return (unsigned short)((u + 0x7FFFu + ((u >> 16) & 1u)) >> 16);   // RNE
}
__device__ __forceinline__ float bf2f(unsigned short h) {
    return __uint_as_float(((unsigned)h) << 16);
}

// split w into bf16 hi/lo, transposed to [n][k]; also wsq (fp32, same order as round-1)
__global__ void prep_kernel(const float* __restrict__ w,
                            unsigned short* __restrict__ wh, unsigned short* __restrict__ wl,
                            float* __restrict__ wsq) {
    int j = threadIdx.x;  // 512
    float s = 0.f;
    for (int d = 0; d < EMB; ++d) {
        float v = w[d * NEMB + j];
        s = fmaf(v, v, s);
        unsigned short h = f2bf(v);
        wh[j * EMB + d] = h;
        wl[j * EMB + d] = f2bf(v - bf2f(h));
    }
    wsq[j] = s;
}

// block = 256 tokens (4 h-rows), 4 waves x 64 tokens. Split-bf16 MFMA distances.
__global__ __launch_bounds__(256, 2) void vq_main(
    const float* __restrict__ x, const float* __restrict__ w,
    const unsigned short* __restrict__ wh, const unsigned short* __restrict__ wl,
    const float* __restrict__ wsq,
    float* __restrict__ out_result, float* __restrict__ out_arg,
    float* __restrict__ cnt, float* __restrict__ es,
    unsigned* __restrict__ flagcnt, unsigned* __restrict__ flaglist)
{
    __shared__ __align__(16) float xt[EMB * 256];   // [d][m] 64 KB
    __shared__ float xsq_s[256];
    __shared__ float wsq_s[NEMB];
    __shared__ int jmin_s[256];

    const int tid = threadIdx.x;
    const int blk = blockIdx.x;          // 512
    const int b  = blk >> 4;
    const int h0 = (blk & 15) << 2;      // 4 rows
    const int t0 = b * 4096 + h0 * 64;   // global token base
    const float* xbase = x + b * BSTR + h0 * 64;

    // stage x tile [d][m], coalesced float4
#pragma unroll
    for (int it = 0; it < 16; ++it) {
        int idx = tid + (it << 8);       // float4 idx 0..4095
        int d = idx >> 6, mq = idx & 63;
        float4 v = *(const float4*)(xbase + d * 4096 + (mq << 2));
        *(float4*)(xt + d * 256 + (mq << 2)) = v;
    }
    wsq_s[tid] = wsq[tid];
    wsq_s[tid + 256] = wsq[tid + 256];
    __syncthreads();

    {
        float s = 0.f;
#pragma unroll
        for (int d = 0; d < EMB; ++d) { float v = xt[d * 256 + tid]; s = fmaf(v, v, s); }
        xsq_s[tid] = s;
    }
    __syncthreads();

    const int lane = tid & 63;
    const int wave = tid >> 6;
    const int l15  = lane & 15;
    const int quad = lane >> 4;
    const int wbase = wave << 6;         // 64 tokens per wave

    // build A fragments once (hi/lo), reused across all code chunks
    bf16x8 ah[4][2], al[4][2];
#pragma unroll
    for (int mt = 0; mt < 4; ++mt) {
        int m = wbase + (mt << 4) + l15;
#pragma unroll
        for (int ks = 0; ks < 2; ++ks) {
            int k0 = (ks << 5) + (quad << 3);
            bf16x8 hh, ll;
#pragma unroll
            for (int i = 0; i < 8; ++i) {
                float v = xt[(k0 + i) * 256 + m];
                unsigned short h = f2bf(v);
                hh[i] = (short)h;
                ll[i] = (short)f2bf(v - bf2f(h));
            }
            ah[mt][ks] = hh; al[mt][ks] = ll;
        }
    }

    float xq[4][4];
#pragma unroll
    for (int mt = 0; mt < 4; ++mt)
#pragma unroll
        for (int r = 0; r < 4; ++r)
            xq[mt][r] = xsq_s[wbase + (mt << 4) + (quad << 2) + r];

    // packed keys: fp32 dist with low 9 bits = code index
    unsigned k1[4][4], k2[4][4];
#pragma unroll
    for (int mt = 0; mt < 4; ++mt)
#pragma unroll
        for (int r = 0; r < 4; ++r) { k1[mt][r] = 0xFFFFFFFFu; k2[mt][r] = 0xFFFFFFFFu; }

    for (int c = 0; c < 8; ++c) {
#pragma unroll
        for (int nt = 0; nt < 4; ++nt) {
            int n = (c << 6) + (nt << 4) + l15;
            const unsigned short* ph = wh + n * EMB;
            const unsigned short* pl = wl + n * EMB;
            bf16x8 bh0 = *(const bf16x8*)(ph + (quad << 3));
            bf16x8 bh1 = *(const bf16x8*)(ph + 32 + (quad << 3));
            bf16x8 bl0 = *(const bf16x8*)(pl + (quad << 3));
            bf16x8 bl1 = *(const bf16x8*)(pl + 32 + (quad << 3));
            float wq = wsq_s[n];

            f32x4 acc[4];
#pragma unroll
            for (int mt = 0; mt < 4; ++mt) acc[mt] = (f32x4){0.f, 0.f, 0.f, 0.f};
#pragma unroll
            for (int mt = 0; mt < 4; ++mt) {
                acc[mt] = __builtin_amdgcn_mfma_f32_16x16x32_bf16(ah[mt][0], bh0, acc[mt], 0, 0, 0);
                acc[mt] = __builtin_amdgcn_mfma_f32_16x16x32_bf16(ah[mt][1], bh1, acc[mt], 0, 0, 0);
                acc[mt] = __builtin_amdgcn_mfma_f32_16x16x32_bf16(ah[mt][0], bl0, acc[mt], 0, 0, 0);
                acc[mt] = __builtin_amdgcn_mfma_f32_16x16x32_bf16(ah[mt][1], bl1, acc[mt], 0, 0, 0);
                acc[mt] = __builtin_amdgcn_mfma_f32_16x16x32_bf16(al[mt][0], bh0, acc[mt], 0, 0, 0);
                acc[mt] = __builtin_amdgcn_mfma_f32_16x16x32_bf16(al[mt][1], bh1, acc[mt], 0, 0, 0);
            }
#pragma unroll
            for (int mt = 0; mt < 4; ++mt)
#pragma unroll
                for (int r = 0; r < 4; ++r) {
                    float s = fmaf(-2.f, acc[mt][r], xq[mt][r] + wq);
                    s = fmaxf(s, 0.f);
                    unsigned key = (__float_as_uint(s) & 0xFFFFFE00u) | (unsigned)n;
                    unsigned mx = max(k1[mt][r], key);
                    k1[mt][r] = min(k1[mt][r], key);
                    k2[mt][r] = min(k2[mt][r], min(mx, k2[mt][r]) == k2[mt][r] ? mx : mx); // see below
                    k2[mt][r] = min(k2[mt][r], mx);
                }
        }
    }

    // butterfly top-2 merge across the 16 lanes sharing each token
#pragma unroll
    for (int mt = 0; mt < 4; ++mt)
#pragma unroll
        for (int r = 0; r < 4; ++r) {
            unsigned v1 = k1[mt][r], v2 = k2[mt][r];
#pragma unroll
            for (int msk = 1; msk < 16; msk <<= 1) {
                unsigned c1 = __shfl_xor(v1, msk, 64);
                unsigned c2 = __shfl_xor(v2, msk, 64);
                unsigned mx = max(v1, c1);
                v1 = min(v1, c1);
                v2 = min(mx, min(v2, c2));
            }
            k1[mt][r] = v1; k2[mt][r] = v2;
        }

    if (l15 == 0) {
#pragma unroll
        for (int mt = 0; mt < 4; ++mt)
#pragma unroll
            for (int r = 0; r < 4; ++r) {
                int mlocal = wbase + (mt << 4) + (quad << 2) + r;
                unsigned a = k1[mt][r], bb = k2[mt][r];
                int j1 = (int)(a & 511u);
                float s1 = __uint_as_float(a & 0xFFFFFE00u);
                float s2 = __uint_as_float(bb & 0xFFFFFE00u);
                bool flag = (s2 - s1) < GAP_T;
                jmin_s[mlocal] = j1 | (flag ? (int)0x80000000 : 0);
                out_arg[t0 + mlocal] = (float)j1;
                if (flag) {
                    unsigned idx = atomicAdd(flagcnt, 1u);
                    flaglist[idx] = (unsigned)(t0 + mlocal);
                } else {
                    atomicAdd(&cnt[j1], 1.0f);
                }
            }
    }
    __syncthreads();

    // epilogue for unflagged tokens: result gather + embed_sum scatter
    const int obase = b * BSTR + h0 * 64;
#pragma unroll 4
    for (int i = 0; i < 64; ++i) {
        int idx = tid + (i << 8);
        int d = idx >> 8, m = idx & 255;
        int jf = jmin_s[m];
        if (jf >= 0) {
            out_result[obase + d * 4096 + m] = w[d * NEMB + jf];
            atomicAdd(&es[d * NEMB + jf], xt[d * 256 + m]);
        }
    }
}

// exact fp32 (+f64 tie) re-decision for flagged tokens; owns their outputs/EMA
__global__ __launch_bounds__(256) void refine_kernel(
    const float* __restrict__ x, const float* __restrict__ w, const float* __restrict__ wsq,
    const unsigned* __restrict__ flagcnt, const unsigned* __restrict__ flaglist,
    float* __restrict__ out_result, float* __restrict__ out_arg,
    float* __restrict__ cnt, float* __restrict__ es)
{
    __shared__ float xs[EMB];
    __shared__ float xsq_sh;
    __shared__ float rs1[256], rs2[256];
    __shared__ int   rj1[256], rj2[256];
    __shared__ int   jfin;

    const unsigned count = *flagcnt;
    const int tid = threadIdx.x;

    for (unsigned g = blockIdx.x; g < count; g += gridDim.x) {
        unsigned t = flaglist[g];
        int b = (int)(t >> 12), hw = (int)(t & 4095u);
        if (tid < EMB) xs[tid] = x[b * BSTR + tid * 4096 + hw];
        __syncthreads();
        if (tid == 0) {
            float s = 0.f;
            for (int d = 0; d < EMB; ++d) s = fmaf(xs[d], xs[d], s);
            xsq_sh = s;
        }
        __syncthreads();
        float xq = xsq_sh;

        float S1 = 3.4e38f, S2 = 3.4e38f; int J1 = 0, J2 = 0;
#define UPD(s_, j_) do { \
        if (s_ < S1 || (s_ == S1 && j_ < J1)) { S2 = S1; J2 = J1; S1 = s_; J1 = j_; } \
        else if (s_ < S2 || (s_ == S2 && j_ < J2)) { S2 = s_; J2 = j_; } } while (0)
#pragma unroll
        for (int p = 0; p < 2; ++p) {
            int j = tid + (p << 8);
            float acc = 0.f;
#pragma unroll
            for (int d = 0; d < EMB; ++d) acc = fmaf(xs[d], w[d * NEMB + j], acc);
            float s = (xq - 2.f * acc) + wsq[j];
            UPD(s, j);
        }
        rs1[tid] = S1; rj1[tid] = J1; rs2[tid] = S2; rj2[tid] = J2;
        __syncthreads();
        for (int st = 128; st > 0; st >>= 1) {
            if (tid < st) {
                S1 = rs1[tid]; J1 = rj1[tid]; S2 = rs2[tid]; J2 = rj2[tid];
                float sa = rs1[tid + st]; int ja = rj1[tid + st];
                float sb = rs2[tid + st]; int jb = rj2[tid + st];
                UPD(sa, ja);
                UPD(sb, jb);
                rs1[tid] = S1; rj1[tid] = J1; rs2[tid] = S2; rj2[tid] = J2;
            }
            __syncthreads();
        }
#undef UPD
        if (tid == 0) {
            int jm = rj1[0];
            if (rs2[0] - rs1[0] < 1e-3f) {
                int Ja = rj1[0], Jb = rj2[0];
                double dot1 = 0.0, dot2 = 0.0, sq1 = 0.0, sq2 = 0.0;
                for (int d = 0; d < EMB; ++d) {
                    double xv = (double)xs[d];
                    double w1 = (double)w[d * NEMB + Ja];
                    double w2 = (double)w[d * NEMB + Jb];
                    dot1 = fma(xv, w1, dot1); sq1 = fma(w1, w1, sq1);
                    dot2 = fma(xv, w2, dot2); sq2 = fma(w2, w2, sq2);
                }
                double e1 = sq1 - 2.0 * dot1;
                double e2 = sq2 - 2.0 * dot2;
                if (e2 < e1 || (e2 == e1 && Jb < Ja)) jm = Jb;
            }
            jfin = jm;
        }
        __syncthreads();
        int j = jfin;
        if (tid < EMB) {
            out_result[b * BSTR + tid * 4096 + hw] = w[tid * NEMB + j];
            atomicAdd(&es[tid * NEMB + j], xs[tid]);
        }
        if (tid == 64) { out_arg[t] = (float)j; atomicAdd(&cnt[j], 1.0f); }
        __syncthreads();
    }
}

__global__ void finalize_cs(const float* __restrict__ cs_in, float* __restrict__ ncs_io,
                            float* __restrict__ ws_n) {
    __shared__ float red[NEMB];
    int j = threadIdx.x;
    float cval = ncs_io[j];
    float nidx = (cval == 0.f) ? 1.f : cval;
    float ncs = DECAYF * cs_in[j] + OMDF * nidx;
    ncs_io[j] = ncs;
    red[j] = ncs;
    __syncthreads();
    for (int s = 256; s > 0; s >>= 1) {
        if (j < s) red[j] += red[j + s];
        __syncthreads();
    }
    if (j == 0) ws_n[0] = red[0];
}

__global__ void finalize_w(const float* __restrict__ avg_in,
                           const float* __restrict__ ncs, const float* __restrict__ ws_n,
                           float* __restrict__ out_w, float* __restrict__ avg_io) {
    int d = blockIdx.x, j = threadIdx.x;
    float n = ws_n[0];
    float ncsj = ncs[j];
    float csj = (ncsj + EPSF) / (n + (float)NEMB * EPSF) * n;
    float esv = avg_io[d * NEMB + j];
    float navg = DECAYF * avg_in[d * NEMB + j] + OMDF * esv;
    avg_io[d * NEMB + j] = navg;
    out_w[d * NEMB + j] = navg / csj;
}

extern "C" void kernel_launch(void* const* d_in, const int* in_sizes, int n_in,
                              void* d_out, int out_size, void* d_ws, size_t ws_size,
                              hipStream_t stream) {
    (void)in_sizes; (void)n_in; (void)out_size; (void)ws_size;
    const float* x   = (const float*)d_in[0];
    const float* w   = (const float*)d_in[1];
    const float* cs  = (const float*)d_in[2];
    const float* avg = (const float*)d_in[3];

    float* out = (float*)d_out;
    float* out_result = out;                 // 8388608
    float* out_arg    = out + 8388608;       // 131072
    float* out_w      = out + 8519680;       // 32768
    float* out_ncs    = out + 8552448;       // 512   (counts accumulate here)
    float* out_avg    = out + 8552960;       // 32768 (embed_sum accumulates here)

    char* wsb = (char*)d_ws;
    unsigned short* wh = (unsigned short*)wsb;             // 65536 B
    unsigned short* wl = (unsigned short*)(wsb + 65536);   // 65536 B
    float* wsq  = (float*)(wsb + 131072);                  // 2048 B
    float* ws_n = (float*)(wsb + 133120);                  // 4 B
    unsigned* flagcnt  = (unsigned*)(wsb + 133632);        // 4 B
    unsigned* flaglist = (unsigned*)(wsb + 134144);        // 524288 B

    hipMemsetAsync(out_ncs, 0, (size_t)33280 * sizeof(float), stream);
    hipMemsetAsync(flagcnt, 0, sizeof(unsigned), stream);
    prep_kernel<<<1, 512, 0, stream>>>(w, wh, wl, wsq);
    vq_main<<<512, 256, 0, stream>>>(x, w, wh, wl, wsq, out_result, out_arg,
                                     out_ncs, out_avg, flagcnt, flaglist);
    refine_kernel<<<256, 256, 0, stream>>>(x, w, wsq, flagcnt, flaglist,
                                           out_result, out_arg, out_ncs, out_avg);
    finalize_cs<<<1, 512, 0, stream>>>(cs, out_ncs, ws_n);
    finalize_w<<<64, 512, 0, stream>>>(avg, out_ncs, ws_n, out_w, out_avg);
}

// Round 3
// 482.908 us; speedup vs baseline: 1.5756x; 1.5756x over previous
//
#include <hip/hip_runtime.h>

#define NEMB 512
#define EMB 64
#define BSTR 262144          // 64*4096
#define DECAYF 0.99f
#define OMDF 0.01f
#define EPSF 1e-5f
#define GAP_T 0.125f

typedef __attribute__((ext_vector_type(8))) short bf16x8;
typedef __attribute__((ext_vector_type(4))) float f32x4;

__device__ __forceinline__ unsigned short f2bf(float f) {
    unsigned u = __float_as_uint(f);
    return (unsigned short)((u + 0x7FFFu + ((u >> 16) & 1u)) >> 16);   // RNE
}
__device__ __forceinline__ float bf2f(unsigned short h) {
    return __uint_as_float(((unsigned)h) << 16);
}

// split w into bf16 hi/lo, transposed to [n][k]; also wsq
__global__ void prep_kernel(const float* __restrict__ w,
                            unsigned short* __restrict__ wh, unsigned short* __restrict__ wl,
                            float* __restrict__ wsq) {
    int j = threadIdx.x;  // 512
    float s = 0.f;
    for (int d = 0; d < EMB; ++d) {
        float v = w[d * NEMB + j];
        s = fmaf(v, v, s);
        unsigned short h = f2bf(v);
        wh[j * EMB + d] = h;
        wl[j * EMB + d] = f2bf(v - bf2f(h));
    }
    wsq[j] = s;
}

// block = 256 tokens (4 h-rows), 4 waves x 64 tokens. Split-bf16 MFMA distances.
// NO es/cnt atomics here anymore — that was the 480 us stall.
__global__ __launch_bounds__(256, 2) void vq_main(
    const float* __restrict__ x, const float* __restrict__ w,
    const unsigned short* __restrict__ wh, const unsigned short* __restrict__ wl,
    const float* __restrict__ wsq,
    float* __restrict__ out_result, float* __restrict__ out_arg,
    unsigned* __restrict__ flagcnt, unsigned* __restrict__ flaglist)
{
    __shared__ __align__(16) float xt[EMB * 256];   // [d][m] 64 KB
    __shared__ float xsq_s[256];
    __shared__ float wsq_s[NEMB];
    __shared__ int jmin_s[256];

    const int tid = threadIdx.x;
    const int blk = blockIdx.x;          // 512
    const int b  = blk >> 4;
    const int h0 = (blk & 15) << 2;      // 4 rows
    const int t0 = b * 4096 + h0 * 64;   // global token base
    const float* xbase = x + b * BSTR + h0 * 64;

#pragma unroll
    for (int it = 0; it < 16; ++it) {
        int idx = tid + (it << 8);       // float4 idx 0..4095
        int d = idx >> 6, mq = idx & 63;
        float4 v = *(const float4*)(xbase + d * 4096 + (mq << 2));
        *(float4*)(xt + d * 256 + (mq << 2)) = v;
    }
    wsq_s[tid] = wsq[tid];
    wsq_s[tid + 256] = wsq[tid + 256];
    __syncthreads();

    {
        float s = 0.f;
#pragma unroll
        for (int d = 0; d < EMB; ++d) { float v = xt[d * 256 + tid]; s = fmaf(v, v, s); }
        xsq_s[tid] = s;
    }
    __syncthreads();

    const int lane = tid & 63;
    const int wave = tid >> 6;
    const int l15  = lane & 15;
    const int quad = lane >> 4;
    const int wbase = wave << 6;         // 64 tokens per wave

    // A fragments once (hi/lo), reused across all code chunks
    bf16x8 ah[4][2], al[4][2];
#pragma unroll
    for (int mt = 0; mt < 4; ++mt) {
        int m = wbase + (mt << 4) + l15;
#pragma unroll
        for (int ks = 0; ks < 2; ++ks) {
            int k0 = (ks << 5) + (quad << 3);
            bf16x8 hh, ll;
#pragma unroll
            for (int i = 0; i < 8; ++i) {
                float v = xt[(k0 + i) * 256 + m];
                unsigned short h = f2bf(v);
                hh[i] = (short)h;
                ll[i] = (short)f2bf(v - bf2f(h));
            }
            ah[mt][ks] = hh; al[mt][ks] = ll;
        }
    }

    float xq[4][4];
#pragma unroll
    for (int mt = 0; mt < 4; ++mt)
#pragma unroll
        for (int r = 0; r < 4; ++r)
            xq[mt][r] = xsq_s[wbase + (mt << 4) + (quad << 2) + r];

    // packed keys: fp32 dist (low 9 mantissa bits) | code index
    unsigned k1[4][4], k2[4][4];
#pragma unroll
    for (int mt = 0; mt < 4; ++mt)
#pragma unroll
        for (int r = 0; r < 4; ++r) { k1[mt][r] = 0xFFFFFFFFu; k2[mt][r] = 0xFFFFFFFFu; }

    for (int c = 0; c < 8; ++c) {
#pragma unroll
        for (int nt = 0; nt < 4; ++nt) {
            int n = (c << 6) + (nt << 4) + l15;
            const unsigned short* ph = wh + n * EMB;
            const unsigned short* pl = wl + n * EMB;
            bf16x8 bh0 = *(const bf16x8*)(ph + (quad << 3));
            bf16x8 bh1 = *(const bf16x8*)(ph + 32 + (quad << 3));
            bf16x8 bl0 = *(const bf16x8*)(pl + (quad << 3));
            bf16x8 bl1 = *(const bf16x8*)(pl + 32 + (quad << 3));
            float wq = wsq_s[n];

            f32x4 acc[4];
#pragma unroll
            for (int mt = 0; mt < 4; ++mt) acc[mt] = (f32x4){0.f, 0.f, 0.f, 0.f};
#pragma unroll
            for (int mt = 0; mt < 4; ++mt) {
                acc[mt] = __builtin_amdgcn_mfma_f32_16x16x32_bf16(ah[mt][0], bh0, acc[mt], 0, 0, 0);
                acc[mt] = __builtin_amdgcn_mfma_f32_16x16x32_bf16(ah[mt][1], bh1, acc[mt], 0, 0, 0);
                acc[mt] = __builtin_amdgcn_mfma_f32_16x16x32_bf16(ah[mt][0], bl0, acc[mt], 0, 0, 0);
                acc[mt] = __builtin_amdgcn_mfma_f32_16x16x32_bf16(ah[mt][1], bl1, acc[mt], 0, 0, 0);
                acc[mt] = __builtin_amdgcn_mfma_f32_16x16x32_bf16(al[mt][0], bh0, acc[mt], 0, 0, 0);
                acc[mt] = __builtin_amdgcn_mfma_f32_16x16x32_bf16(al[mt][1], bh1, acc[mt], 0, 0, 0);
            }
#pragma unroll
            for (int mt = 0; mt < 4; ++mt)
#pragma unroll
                for (int r = 0; r < 4; ++r) {
                    float s = fmaf(-2.f, acc[mt][r], xq[mt][r] + wq);
                    s = fmaxf(s, 0.f);
                    unsigned key = (__float_as_uint(s) & 0xFFFFFE00u) | (unsigned)n;
                    unsigned mx = max(k1[mt][r], key);
                    k1[mt][r] = min(k1[mt][r], key);
                    k2[mt][r] = min(k2[mt][r], mx);
                }
        }
    }

    // butterfly top-2 merge across the 16 lanes sharing each token
#pragma unroll
    for (int mt = 0; mt < 4; ++mt)
#pragma unroll
        for (int r = 0; r < 4; ++r) {
            unsigned v1 = k1[mt][r], v2 = k2[mt][r];
#pragma unroll
            for (int msk = 1; msk < 16; msk <<= 1) {
                unsigned c1 = __shfl_xor(v1, msk, 64);
                unsigned c2 = __shfl_xor(v2, msk, 64);
                unsigned mx = max(v1, c1);
                v1 = min(v1, c1);
                v2 = min(mx, min(v2, c2));
            }
            k1[mt][r] = v1; k2[mt][r] = v2;
        }

    if (l15 == 0) {
#pragma unroll
        for (int mt = 0; mt < 4; ++mt)
#pragma unroll
            for (int r = 0; r < 4; ++r) {
                int mlocal = wbase + (mt << 4) + (quad << 2) + r;
                unsigned a = k1[mt][r], bb = k2[mt][r];
                int j1 = (int)(a & 511u);
                float s1 = __uint_as_float(a & 0xFFFFFE00u);
                float s2 = __uint_as_float(bb & 0xFFFFFE00u);
                jmin_s[mlocal] = j1;
                out_arg[t0 + mlocal] = (float)j1;
                if (s2 - s1 < GAP_T) {
                    unsigned idx = atomicAdd(flagcnt, 1u);
                    flaglist[idx] = (unsigned)(t0 + mlocal);
                }
            }
    }
    __syncthreads();

    // epilogue: quantized result gather only (refine overwrites flagged columns later)
    const int obase = b * BSTR + h0 * 64;
    int jme = jmin_s[tid];
#pragma unroll 8
    for (int d = 0; d < EMB; ++d)
        out_result[obase + d * 4096 + tid] = w[d * NEMB + jme];
}

// exact fp32 (+f64 tie) re-decision for flagged tokens; fixes out_arg/out_result only
__global__ __launch_bounds__(256) void refine_kernel(
    const float* __restrict__ x, const float* __restrict__ w, const float* __restrict__ wsq,
    const unsigned* __restrict__ flagcnt, const unsigned* __restrict__ flaglist,
    float* __restrict__ out_result, float* __restrict__ out_arg)
{
    __shared__ float xs[EMB];
    __shared__ float xsq_sh;
    __shared__ float rs1[256], rs2[256];
    __shared__ int   rj1[256], rj2[256];
    __shared__ int   jfin;

    const unsigned count = *flagcnt;
    const int tid = threadIdx.x;

    for (unsigned g = blockIdx.x; g < count; g += gridDim.x) {
        unsigned t = flaglist[g];
        int b = (int)(t >> 12), hw = (int)(t & 4095u);
        if (tid < EMB) xs[tid] = x[b * BSTR + tid * 4096 + hw];
        __syncthreads();
        if (tid == 0) {
            float s = 0.f;
            for (int d = 0; d < EMB; ++d) s = fmaf(xs[d], xs[d], s);
            xsq_sh = s;
        }
        __syncthreads();
        float xq = xsq_sh;

        float S1 = 3.4e38f, S2 = 3.4e38f; int J1 = 0, J2 = 0;
#define UPD(s_, j_) do { \
        if (s_ < S1 || (s_ == S1 && j_ < J1)) { S2 = S1; J2 = J1; S1 = s_; J1 = j_; } \
        else if (s_ < S2 || (s_ == S2 && j_ < J2)) { S2 = s_; J2 = j_; } } while (0)
#pragma unroll
        for (int p = 0; p < 2; ++p) {
            int j = tid + (p << 8);
            float acc = 0.f;
#pragma unroll
            for (int d = 0; d < EMB; ++d) acc = fmaf(xs[d], w[d * NEMB + j], acc);
            float s = (xq - 2.f * acc) + wsq[j];
            UPD(s, j);
        }
        rs1[tid] = S1; rj1[tid] = J1; rs2[tid] = S2; rj2[tid] = J2;
        __syncthreads();
        for (int st = 128; st > 0; st >>= 1) {
            if (tid < st) {
                S1 = rs1[tid]; J1 = rj1[tid]; S2 = rs2[tid]; J2 = rj2[tid];
                float sa = rs1[tid + st]; int ja = rj1[tid + st];
                float sb = rs2[tid + st]; int jb = rj2[tid + st];
                UPD(sa, ja);
                UPD(sb, jb);
                rs1[tid] = S1; rj1[tid] = J1; rs2[tid] = S2; rj2[tid] = J2;
            }
            __syncthreads();
        }
#undef UPD
        if (tid == 0) {
            int jm = rj1[0];
            if (rs2[0] - rs1[0] < 1e-3f) {
                int Ja = rj1[0], Jb = rj2[0];
                double dot1 = 0.0, dot2 = 0.0, sq1 = 0.0, sq2 = 0.0;
                for (int d = 0; d < EMB; ++d) {
                    double xv = (double)xs[d];
                    double w1 = (double)w[d * NEMB + Ja];
                    double w2 = (double)w[d * NEMB + Jb];
                    dot1 = fma(xv, w1, dot1); sq1 = fma(w1, w1, sq1);
                    dot2 = fma(xv, w2, dot2); sq2 = fma(w2, w2, sq2);
                }
                double e1 = sq1 - 2.0 * dot1;
                double e2 = sq2 - 2.0 * dot2;
                if (e2 < e1 || (e2 == e1 && Jb < Ja)) jm = Jb;
            }
            jfin = jm;
        }
        __syncthreads();
        int j = jfin;
        if (tid < EMB) out_result[b * BSTR + tid * 4096 + hw] = w[tid * NEMB + j];
        if (tid == 64) out_arg[t] = (float)j;
        __syncthreads();
    }
}

// segmented-sum gather: grid = 65 groups x 4 token-chunks.
// grp<64: es[grp][j] partial over chunk; grp==64: counts. LDS accumulate, flush w/ global atomics.
__global__ __launch_bounds__(256) void scatter_es(
    const float* __restrict__ x, const float* __restrict__ arg,
    float* __restrict__ cnt, float* __restrict__ es)
{
    __shared__ float acc[NEMB];
    const int tid = threadIdx.x;
    const int grp = blockIdx.x >> 2;     // 0..64
    const int chunk = blockIdx.x & 3;

    acc[tid] = 0.f; acc[tid + 256] = 0.f;
    __syncthreads();

    const int tbase = chunk * 32768;
    if (grp < 64) {
        const int d = grp;
        for (int it = 0; it < 128; ++it) {
            int t = tbase + (it << 8) + tid;
            int j = (int)arg[t];
            float v = x[(t >> 12) * BSTR + d * 4096 + (t & 4095)];
            atomicAdd(&acc[j], v);
        }
    } else {
        for (int it = 0; it < 128; ++it) {
            int t = tbase + (it << 8) + tid;
            int j = (int)arg[t];
            atomicAdd(&acc[j], 1.0f);
        }
    }
    __syncthreads();

    float* dst = (grp < 64) ? (es + grp * NEMB) : cnt;
#pragma unroll
    for (int k = 0; k < 2; ++k) {
        int j = tid + (k << 8);
        float v = acc[j];
        if (v != 0.f) atomicAdd(&dst[j], v);
    }
}

__global__ void finalize_cs(const float* __restrict__ cs_in, float* __restrict__ ncs_io,
                            float* __restrict__ ws_n) {
    __shared__ float red[NEMB];
    int j = threadIdx.x;
    float cval = ncs_io[j];
    float nidx = (cval == 0.f) ? 1.f : cval;
    float ncs = DECAYF * cs_in[j] + OMDF * nidx;
    ncs_io[j] = ncs;
    red[j] = ncs;
    __syncthreads();
    for (int s = 256; s > 0; s >>= 1) {
        if (j < s) red[j] += red[j + s];
        __syncthreads();
    }
    if (j == 0) ws_n[0] = red[0];
}

__global__ void finalize_w(const float* __restrict__ avg_in,
                           const float* __restrict__ ncs, const float* __restrict__ ws_n,
                           float* __restrict__ out_w, float* __restrict__ avg_io) {
    int d = blockIdx.x, j = threadIdx.x;
    float n = ws_n[0];
    float ncsj = ncs[j];
    float csj = (ncsj + EPSF) / (n + (float)NEMB * EPSF) * n;
    float esv = avg_io[d * NEMB + j];
    float navg = DECAYF * avg_in[d * NEMB + j] + OMDF * esv;
    avg_io[d * NEMB + j] = navg;
    out_w[d * NEMB + j] = navg / csj;
}

extern "C" void kernel_launch(void* const* d_in, const int* in_sizes, int n_in,
                              void* d_out, int out_size, void* d_ws, size_t ws_size,
                              hipStream_t stream) {
    (void)in_sizes; (void)n_in; (void)out_size; (void)ws_size;
    const float* x   = (const float*)d_in[0];
    const float* w   = (const float*)d_in[1];
    const float* cs  = (const float*)d_in[2];
    const float* avg = (const float*)d_in[3];

    float* out = (float*)d_out;
    float* out_result = out;                 // 8388608
    float* out_arg    = out + 8388608;       // 131072
    float* out_w      = out + 8519680;       // 32768
    float* out_ncs    = out + 8552448;       // 512   (counts accumulate here)
    float* out_avg    = out + 8552960;       // 32768 (embed_sum accumulates here)

    char* wsb = (char*)d_ws;
    unsigned short* wh = (unsigned short*)wsb;             // 65536 B
    unsigned short* wl = (unsigned short*)(wsb + 65536);   // 65536 B
    float* wsq  = (float*)(wsb + 131072);                  // 2048 B
    float* ws_n = (float*)(wsb + 133120);                  // 4 B
    unsigned* flagcnt  = (unsigned*)(wsb + 133632);        // 4 B
    unsigned* flaglist = (unsigned*)(wsb + 134144);        // up to 524288 B

    hipMemsetAsync(out_ncs, 0, (size_t)33280 * sizeof(float), stream);
    hipMemsetAsync(flagcnt, 0, sizeof(unsigned), stream);
    prep_kernel<<<1, 512, 0, stream>>>(w, wh, wl, wsq);
    vq_main<<<512, 256, 0, stream>>>(x, w, wh, wl, wsq, out_result, out_arg,
                                     flagcnt, flaglist);
    refine_kernel<<<256, 256, 0, stream>>>(x, w, wsq, flagcnt, flaglist,
                                           out_result, out_arg);
    scatter_es<<<260, 256, 0, stream>>>(x, out_arg, out_ncs, out_avg);
    finalize_cs<<<1, 512, 0, stream>>>(cs, out_ncs, ws_n);
    finalize_w<<<64, 512, 0, stream>>>(avg, out_ncs, ws_n, out_w, out_avg);
}

// Round 4
// 298.277 us; speedup vs baseline: 2.5509x; 1.6190x over previous
//
#include <hip/hip_runtime.h>

#define NEMB 512
#define EMB 64
#define BSTR 262144          // 64*4096
#define DECAYF 0.99f
#define OMDF 0.01f
#define EPSF 1e-5f
#define GAP_T 0.04f

typedef __attribute__((ext_vector_type(8))) short bf16x8;
typedef __attribute__((ext_vector_type(4))) float f32x4;

__device__ __forceinline__ unsigned short f2bf(float f) {
    unsigned u = __float_as_uint(f);
    return (unsigned short)((u + 0x7FFFu + ((u >> 16) & 1u)) >> 16);   // RNE
}
__device__ __forceinline__ float bf2f(unsigned short h) {
    return __uint_as_float(((unsigned)h) << 16);
}

// 8 blocks x 512 threads: block b handles d in [8b, 8b+8); vectorized 16B stores
__global__ void prep_kernel(const float* __restrict__ w,
                            unsigned short* __restrict__ wh, unsigned short* __restrict__ wl) {
    int j = threadIdx.x;
    int d0 = blockIdx.x << 3;
    bf16x8 hb, lb;
#pragma unroll
    for (int i = 0; i < 8; ++i) {
        float v = w[(d0 + i) * NEMB + j];
        unsigned short h = f2bf(v);
        hb[i] = (short)h;
        lb[i] = (short)f2bf(v - bf2f(h));
    }
    *(bf16x8*)(wh + j * EMB + d0) = hb;
    *(bf16x8*)(wl + j * EMB + d0) = lb;
}

__global__ void wsq_kernel(const float* __restrict__ w, float* __restrict__ wsq) {
    int j = threadIdx.x;  // 512
    float s = 0.f;
#pragma unroll
    for (int d = 0; d < EMB; ++d) { float v = w[d * NEMB + j]; s = fmaf(v, v, s); }
    wsq[j] = s;
}

// block = 256 tokens (4 h-rows), 4 waves x 64 tokens. Split-bf16 MFMA distances.
// Pure argmin: no result write, no w gathers, no es/cnt atomics.
__global__ __launch_bounds__(256, 2) void vq_main(
    const float* __restrict__ x,
    const unsigned short* __restrict__ wh, const unsigned short* __restrict__ wl,
    const float* __restrict__ wsq,
    float* __restrict__ out_arg,
    unsigned* __restrict__ flagcnt, unsigned* __restrict__ flaglist)
{
    __shared__ __align__(16) float xt[EMB * 256];   // [d][m] 64 KB
    __shared__ float xsq_s[256];
    __shared__ float wsq_s[NEMB];

    const int tid = threadIdx.x;
    const int blk = blockIdx.x;          // 512
    const int b  = blk >> 4;
    const int h0 = (blk & 15) << 2;      // 4 rows
    const int t0 = b * 4096 + h0 * 64;   // global token base
    const float* xbase = x + b * BSTR + h0 * 64;

#pragma unroll
    for (int it = 0; it < 16; ++it) {
        int idx = tid + (it << 8);       // float4 idx 0..4095
        int d = idx >> 6, mq = idx & 63;
        float4 v = *(const float4*)(xbase + d * 4096 + (mq << 2));
        *(float4*)(xt + d * 256 + (mq << 2)) = v;
    }
    wsq_s[tid] = wsq[tid];
    wsq_s[tid + 256] = wsq[tid + 256];
    __syncthreads();

    {
        float s = 0.f;
#pragma unroll
        for (int d = 0; d < EMB; ++d) { float v = xt[d * 256 + tid]; s = fmaf(v, v, s); }
        xsq_s[tid] = s;
    }
    __syncthreads();

    const int lane = tid & 63;
    const int wave = tid >> 6;
    const int l15  = lane & 15;
    const int quad = lane >> 4;
    const int wbase = wave << 6;         // 64 tokens per wave

    // A fragments once (hi/lo), reused across all code chunks
    bf16x8 ah[4][2], al[4][2];
#pragma unroll
    for (int mt = 0; mt < 4; ++mt) {
        int m = wbase + (mt << 4) + l15;
#pragma unroll
        for (int ks = 0; ks < 2; ++ks) {
            int k0 = (ks << 5) + (quad << 3);
            bf16x8 hh, ll;
#pragma unroll
            for (int i = 0; i < 8; ++i) {
                float v = xt[(k0 + i) * 256 + m];
                unsigned short h = f2bf(v);
                hh[i] = (short)h;
                ll[i] = (short)f2bf(v - bf2f(h));
            }
            ah[mt][ks] = hh; al[mt][ks] = ll;
        }
    }

    float xq[4][4];
#pragma unroll
    for (int mt = 0; mt < 4; ++mt)
#pragma unroll
        for (int r = 0; r < 4; ++r)
            xq[mt][r] = xsq_s[wbase + (mt << 4) + (quad << 2) + r];

    // packed keys: fp32 dist ROUNDED to 23-9 bits | code index (9 bits)
    unsigned k1[4][4], k2[4][4];
#pragma unroll
    for (int mt = 0; mt < 4; ++mt)
#pragma unroll
        for (int r = 0; r < 4; ++r) { k1[mt][r] = 0xFFFFFFFFu; k2[mt][r] = 0xFFFFFFFFu; }

    for (int c = 0; c < 8; ++c) {
#pragma unroll
        for (int nt = 0; nt < 4; ++nt) {
            int n = (c << 6) + (nt << 4) + l15;
            const unsigned short* ph = wh + n * EMB;
            const unsigned short* pl = wl + n * EMB;
            bf16x8 bh0 = *(const bf16x8*)(ph + (quad << 3));
            bf16x8 bh1 = *(const bf16x8*)(ph + 32 + (quad << 3));
            bf16x8 bl0 = *(const bf16x8*)(pl + (quad << 3));
            bf16x8 bl1 = *(const bf16x8*)(pl + 32 + (quad << 3));
            float wq = wsq_s[n];

            f32x4 acc[4];
#pragma unroll
            for (int mt = 0; mt < 4; ++mt) acc[mt] = (f32x4){0.f, 0.f, 0.f, 0.f};
#pragma unroll
            for (int mt = 0; mt < 4; ++mt) {
                acc[mt] = __builtin_amdgcn_mfma_f32_16x16x32_bf16(ah[mt][0], bh0, acc[mt], 0, 0, 0);
                acc[mt] = __builtin_amdgcn_mfma_f32_16x16x32_bf16(ah[mt][1], bh1, acc[mt], 0, 0, 0);
                acc[mt] = __builtin_amdgcn_mfma_f32_16x16x32_bf16(ah[mt][0], bl0, acc[mt], 0, 0, 0);
                acc[mt] = __builtin_amdgcn_mfma_f32_16x16x32_bf16(ah[mt][1], bl1, acc[mt], 0, 0, 0);
                acc[mt] = __builtin_amdgcn_mfma_f32_16x16x32_bf16(al[mt][0], bh0, acc[mt], 0, 0, 0);
                acc[mt] = __builtin_amdgcn_mfma_f32_16x16x32_bf16(al[mt][1], bh1, acc[mt], 0, 0, 0);
            }
#pragma unroll
            for (int mt = 0; mt < 4; ++mt)
#pragma unroll
                for (int r = 0; r < 4; ++r) {
                    float s = fmaf(-2.f, acc[mt][r], xq[mt][r] + wq);
                    s = fmaxf(s, 0.f);
                    unsigned key = ((__float_as_uint(s) + 0x100u) & 0xFFFFFE00u) | (unsigned)n;
                    unsigned mx = max(k1[mt][r], key);
                    k1[mt][r] = min(k1[mt][r], key);
                    k2[mt][r] = min(k2[mt][r], mx);
                }
        }
    }

    // butterfly top-2 merge across the 16 lanes sharing each token
#pragma unroll
    for (int mt = 0; mt < 4; ++mt)
#pragma unroll
        for (int r = 0; r < 4; ++r) {
            unsigned v1 = k1[mt][r], v2 = k2[mt][r];
#pragma unroll
            for (int msk = 1; msk < 16; msk <<= 1) {
                unsigned c1 = __shfl_xor(v1, msk, 64);
                unsigned c2 = __shfl_xor(v2, msk, 64);
                unsigned mx = max(v1, c1);
                v1 = min(v1, c1);
                v2 = min(mx, min(v2, c2));
            }
            k1[mt][r] = v1; k2[mt][r] = v2;
        }

    if (l15 == 0) {
#pragma unroll
        for (int mt = 0; mt < 4; ++mt)
#pragma unroll
            for (int r = 0; r < 4; ++r) {
                int mlocal = wbase + (mt << 4) + (quad << 2) + r;
                unsigned a = k1[mt][r], bb = k2[mt][r];
                int j1 = (int)(a & 511u);
                float s1 = __uint_as_float(a & 0xFFFFFE00u);
                float s2 = __uint_as_float(bb & 0xFFFFFE00u);
                out_arg[t0 + mlocal] = (float)j1;
                if (s2 - s1 < GAP_T) {
                    unsigned idx = atomicAdd(flagcnt, 1u);
                    if (idx < 131072u) flaglist[idx] = (unsigned)(t0 + mlocal);
                }
            }
    }
}

// wave-per-token exact fp32 (+f64 tie) re-decision; fixes out_arg only
__global__ __launch_bounds__(256) void refine_kernel(
    const float* __restrict__ x, const float* __restrict__ w, const float* __restrict__ wsq,
    const unsigned* __restrict__ flagcnt, const unsigned* __restrict__ flaglist,
    float* __restrict__ out_arg)
{
    const unsigned count = min(*flagcnt, 131072u);
    const int lane = threadIdx.x & 63;
    const unsigned gw = (blockIdx.x << 2) + (unsigned)(threadIdx.x >> 6);
    const unsigned nw = gridDim.x << 2;

#define UPD(s_, j_) do { \
    if (s_ < S1 || (s_ == S1 && j_ < J1)) { S2 = S1; J2 = J1; S1 = s_; J1 = j_; } \
    else if (s_ < S2 || (s_ == S2 && j_ < J2)) { S2 = s_; J2 = j_; } } while (0)

    for (unsigned g = gw; g < count; g += nw) {
        unsigned t = flaglist[g];
        int b = (int)(t >> 12), hw = (int)(t & 4095u);
        float xd = x[b * BSTR + lane * 4096 + hw];

        float xq = xd * xd;
#pragma unroll
        for (int m = 1; m < 64; m <<= 1) xq += __shfl_xor(xq, m, 64);

        float accv[8];
#pragma unroll
        for (int k = 0; k < 8; ++k) accv[k] = 0.f;
#pragma unroll 4
        for (int d = 0; d < EMB; ++d) {
            float xv = __shfl(xd, d, 64);
            const float* wp = w + d * NEMB + lane;
#pragma unroll
            for (int k = 0; k < 8; ++k) accv[k] = fmaf(xv, wp[k << 6], accv[k]);
        }

        float S1 = 3.4e38f, S2 = 3.4e38f; int J1 = 0, J2 = 0;
#pragma unroll
        for (int k = 0; k < 8; ++k) {
            int j = (k << 6) + lane;
            float s = (xq - 2.f * accv[k]) + wsq[j];
            UPD(s, j);
        }
#pragma unroll
        for (int m = 1; m < 64; m <<= 1) {
            float os1 = __shfl_xor(S1, m, 64); int oj1 = __shfl_xor(J1, m, 64);
            float os2 = __shfl_xor(S2, m, 64); int oj2 = __shfl_xor(J2, m, 64);
            UPD(os1, oj1);
            UPD(os2, oj2);
        }

        int jm = J1;
        if (S2 - S1 < 1e-3f) {
            float w1 = w[lane * NEMB + J1];
            float w2 = w[lane * NEMB + J2];
            double e1 = (double)w1 * (double)w1 - 2.0 * (double)xd * (double)w1;
            double e2 = (double)w2 * (double)w2 - 2.0 * (double)xd * (double)w2;
#pragma unroll
            for (int m = 1; m < 64; m <<= 1) {
                e1 += __shfl_xor(e1, m, 64);
                e2 += __shfl_xor(e2, m, 64);
            }
            if (e2 < e1 || (e2 == e1 && J2 < J1)) jm = J2;
        }
        if (lane == 0) out_arg[t] = (float)jm;
    }
#undef UPD
}

// fused: result write + es/cnt partials. grid = 65 grp x 4 chunks.
// grp<64: d=grp. grp==64: counts. No global atomics — per-chunk partials.
__global__ __launch_bounds__(256) void finish_kernel(
    const float* __restrict__ x, const float* __restrict__ w, const float* __restrict__ arg,
    float* __restrict__ out_result,
    float* __restrict__ es_part, float* __restrict__ cnt_part)
{
    __shared__ float wrow[NEMB];
    __shared__ float acc[NEMB];
    const int tid = threadIdx.x;
    const int grp = blockIdx.x >> 2;     // 0..64
    const int chunk = blockIdx.x & 3;

    acc[tid] = 0.f; acc[tid + 256] = 0.f;
    if (grp < 64) {
        wrow[tid] = w[grp * NEMB + tid];
        wrow[tid + 256] = w[grp * NEMB + tid + 256];
    }
    __syncthreads();

    const int tbase = chunk * 32768;
    if (grp < 64) {
        const int d = grp;
        for (int it = 0; it < 128; ++it) {
            int t = tbase + (it << 8) + tid;
            int j = (int)arg[t];
            int b = t >> 12, hw = t & 4095;
            float v = x[b * BSTR + d * 4096 + hw];
            atomicAdd(&acc[j], v);                       // LDS atomic
            out_result[b * BSTR + d * 4096 + hw] = wrow[j];
        }
    } else {
        for (int it = 0; it < 128; ++it) {
            int t = tbase + (it << 8) + tid;
            atomicAdd(&acc[(int)arg[t]], 1.0f);
        }
    }
    __syncthreads();

    if (grp < 64) {
        es_part[chunk * 32768 + grp * NEMB + tid] = acc[tid];
        es_part[chunk * 32768 + grp * NEMB + tid + 256] = acc[tid + 256];
    } else {
        cnt_part[chunk * NEMB + tid] = acc[tid];
        cnt_part[chunk * NEMB + tid + 256] = acc[tid + 256];
    }
}

__global__ void finalize_cs(const float* __restrict__ cs_in, const float* __restrict__ cnt_part,
                            float* __restrict__ out_ncs, float* __restrict__ ws_n) {
    __shared__ float red[NEMB];
    int j = threadIdx.x;
    float c = cnt_part[j] + cnt_part[NEMB + j] + cnt_part[2 * NEMB + j] + cnt_part[3 * NEMB + j];
    float nidx = (c == 0.f) ? 1.f : c;
    float ncs = DECAYF * cs_in[j] + OMDF * nidx;
    out_ncs[j] = ncs;
    red[j] = ncs;
    __syncthreads();
    for (int s = 256; s > 0; s >>= 1) {
        if (j < s) red[j] += red[j + s];
        __syncthreads();
    }
    if (j == 0) ws_n[0] = red[0];
}

__global__ void finalize_w(const float* __restrict__ avg_in, const float* __restrict__ es_part,
                           const float* __restrict__ ncs, const float* __restrict__ ws_n,
                           float* __restrict__ out_w, float* __restrict__ out_avg) {
    int d = blockIdx.x, j = threadIdx.x;
    int o = d * NEMB + j;
    float es = es_part[o] + es_part[32768 + o] + es_part[65536 + o] + es_part[98304 + o];
    float n = ws_n[0];
    float ncsj = ncs[j];
    float csj = (ncsj + EPSF) / (n + (float)NEMB * EPSF) * n;
    float navg = DECAYF * avg_in[o] + OMDF * es;
    out_avg[o] = navg;
    out_w[o] = navg / csj;
}

extern "C" void kernel_launch(void* const* d_in, const int* in_sizes, int n_in,
                              void* d_out, int out_size, void* d_ws, size_t ws_size,
                              hipStream_t stream) {
    (void)in_sizes; (void)n_in; (void)out_size; (void)ws_size;
    const float* x   = (const float*)d_in[0];
    const float* w   = (const float*)d_in[1];
    const float* cs  = (const float*)d_in[2];
    const float* avg = (const float*)d_in[3];

    float* out = (float*)d_out;
    float* out_result = out;                 // 8388608
    float* out_arg    = out + 8388608;       // 131072
    float* out_w      = out + 8519680;       // 32768
    float* out_ncs    = out + 8552448;       // 512
    float* out_avg    = out + 8552960;       // 32768

    char* wsb = (char*)d_ws;
    unsigned short* wh = (unsigned short*)wsb;             // 65536 B
    unsigned short* wl = (unsigned short*)(wsb + 65536);   // 65536 B
    float* wsq      = (float*)(wsb + 131072);              // 2048 B
    float* ws_n     = (float*)(wsb + 133120);              // 4 B
    unsigned* flagcnt = (unsigned*)(wsb + 133376);         // 4 B
    float* cnt_part = (float*)(wsb + 133632);              // 8192 B
    unsigned* flaglist = (unsigned*)(wsb + 141824);        // 524288 B
    float* es_part  = (float*)(wsb + 666112);              // 524288 B

    hipMemsetAsync(flagcnt, 0, sizeof(unsigned), stream);
    prep_kernel<<<8, 512, 0, stream>>>(w, wh, wl);
    wsq_kernel<<<1, 512, 0, stream>>>(w, wsq);
    vq_main<<<512, 256, 0, stream>>>(x, wh, wl, wsq, out_arg, flagcnt, flaglist);
    refine_kernel<<<128, 256, 0, stream>>>(x, w, wsq, flagcnt, flaglist, out_arg);
    finish_kernel<<<260, 256, 0, stream>>>(x, w, out_arg, out_result, es_part, cnt_part);
    finalize_cs<<<1, 512, 0, stream>>>(cs, cnt_part, out_ncs, ws_n);
    finalize_w<<<64, 512, 0, stream>>>(avg, es_part, out_ncs, ws_n, out_w, out_avg);
}

// Round 5
// 253.936 us; speedup vs baseline: 2.9963x; 1.1746x over previous
//
#include <hip/hip_runtime.h>

#define NEMB 512
#define EMB 64
#define BSTR 262144          // 64*4096
#define DECAYF 0.99f
#define OMDF 0.01f
#define EPSF 1e-5f
#define GAP_T 0.012f

typedef __attribute__((ext_vector_type(8))) short bf16x8;
typedef __attribute__((ext_vector_type(4))) float f32x4;

__device__ __forceinline__ unsigned short f2bf(float f) {
    unsigned u = __float_as_uint(f);
    return (unsigned short)((u + 0x7FFFu + ((u >> 16) & 1u)) >> 16);   // RNE
}
__device__ __forceinline__ float bf2f(unsigned short h) {
    return __uint_as_float(((unsigned)h) << 16);
}

// 8 blocks x 512 threads: block b handles d in [8b, 8b+8); vectorized 16B stores
__global__ void prep_kernel(const float* __restrict__ w,
                            unsigned short* __restrict__ wh, unsigned short* __restrict__ wl) {
    int j = threadIdx.x;
    int d0 = blockIdx.x << 3;
    bf16x8 hb, lb;
#pragma unroll
    for (int i = 0; i < 8; ++i) {
        float v = w[(d0 + i) * NEMB + j];
        unsigned short h = f2bf(v);
        hb[i] = (short)h;
        lb[i] = (short)f2bf(v - bf2f(h));
    }
    *(bf16x8*)(wh + j * EMB + d0) = hb;
    *(bf16x8*)(wl + j * EMB + d0) = lb;
}

__global__ void wsq_kernel(const float* __restrict__ w, float* __restrict__ wsq) {
    int j = threadIdx.x;  // 512
    float s = 0.f;
#pragma unroll
    for (int d = 0; d < EMB; ++d) { float v = w[d * NEMB + j]; s = fmaf(v, v, s); }
    wsq[j] = s;
}

#define UPD(S1, J1, S2, J2, s_, j_) do { \
    if (s_ < S1 || (s_ == S1 && j_ < J1)) { S2 = S1; J2 = J1; S1 = s_; J1 = j_; } \
    else if (s_ < S2 || (s_ == S2 && j_ < J2)) { S2 = s_; J2 = j_; } } while (0)

// block = 256 tokens (4 h-rows), 4 waves x 64 tokens. Split-bf16 MFMA distances.
// Exact (float,int) top-2 -> tight GAP_T.
__global__ __launch_bounds__(256, 2) void vq_main(
    const float* __restrict__ x,
    const unsigned short* __restrict__ wh, const unsigned short* __restrict__ wl,
    const float* __restrict__ wsq,
    float* __restrict__ out_arg,
    unsigned* __restrict__ flagcnt, unsigned* __restrict__ flaglist)
{
    __shared__ __align__(16) float xt[EMB * 256];   // [d][m] 64 KB
    __shared__ float xsq_s[256];
    __shared__ float wsq_s[NEMB];

    const int tid = threadIdx.x;
    const int blk = blockIdx.x;          // 512
    const int b  = blk >> 4;
    const int h0 = (blk & 15) << 2;      // 4 rows
    const int t0 = b * 4096 + h0 * 64;   // global token base
    const float* xbase = x + b * BSTR + h0 * 64;

#pragma unroll
    for (int it = 0; it < 16; ++it) {
        int idx = tid + (it << 8);       // float4 idx 0..4095
        int d = idx >> 6, mq = idx & 63;
        float4 v = *(const float4*)(xbase + d * 4096 + (mq << 2));
        *(float4*)(xt + d * 256 + (mq << 2)) = v;
    }
    wsq_s[tid] = wsq[tid];
    wsq_s[tid + 256] = wsq[tid + 256];
    __syncthreads();

    {
        float s = 0.f;
#pragma unroll
        for (int d = 0; d < EMB; ++d) { float v = xt[d * 256 + tid]; s = fmaf(v, v, s); }
        xsq_s[tid] = s;
    }
    __syncthreads();

    const int lane = tid & 63;
    const int wave = tid >> 6;
    const int l15  = lane & 15;
    const int quad = lane >> 4;
    const int wbase = wave << 6;         // 64 tokens per wave

    // A fragments once (hi/lo), reused across all code chunks
    bf16x8 ah[4][2], al[4][2];
#pragma unroll
    for (int mt = 0; mt < 4; ++mt) {
        int m = wbase + (mt << 4) + l15;
#pragma unroll
        for (int ks = 0; ks < 2; ++ks) {
            int k0 = (ks << 5) + (quad << 3);
            bf16x8 hh, ll;
#pragma unroll
            for (int i = 0; i < 8; ++i) {
                float v = xt[(k0 + i) * 256 + m];
                unsigned short h = f2bf(v);
                hh[i] = (short)h;
                ll[i] = (short)f2bf(v - bf2f(h));
            }
            ah[mt][ks] = hh; al[mt][ks] = ll;
        }
    }

    float xq[4][4];
#pragma unroll
    for (int mt = 0; mt < 4; ++mt)
#pragma unroll
        for (int r = 0; r < 4; ++r)
            xq[mt][r] = xsq_s[wbase + (mt << 4) + (quad << 2) + r];

    float S1[4][4], S2[4][4];
    int   J1[4][4], J2[4][4];
#pragma unroll
    for (int mt = 0; mt < 4; ++mt)
#pragma unroll
        for (int r = 0; r < 4; ++r) { S1[mt][r] = 3.4e38f; S2[mt][r] = 3.4e38f; J1[mt][r] = 0; J2[mt][r] = 0; }

    for (int c = 0; c < 8; ++c) {
#pragma unroll
        for (int nt = 0; nt < 4; ++nt) {
            int n = (c << 6) + (nt << 4) + l15;
            const unsigned short* ph = wh + n * EMB;
            const unsigned short* pl = wl + n * EMB;
            bf16x8 bh0 = *(const bf16x8*)(ph + (quad << 3));
            bf16x8 bh1 = *(const bf16x8*)(ph + 32 + (quad << 3));
            bf16x8 bl0 = *(const bf16x8*)(pl + (quad << 3));
            bf16x8 bl1 = *(const bf16x8*)(pl + 32 + (quad << 3));
            float wq = wsq_s[n];

            f32x4 acc[4];
#pragma unroll
            for (int mt = 0; mt < 4; ++mt) acc[mt] = (f32x4){0.f, 0.f, 0.f, 0.f};
#pragma unroll
            for (int mt = 0; mt < 4; ++mt) {
                acc[mt] = __builtin_amdgcn_mfma_f32_16x16x32_bf16(ah[mt][0], bh0, acc[mt], 0, 0, 0);
                acc[mt] = __builtin_amdgcn_mfma_f32_16x16x32_bf16(ah[mt][1], bh1, acc[mt], 0, 0, 0);
                acc[mt] = __builtin_amdgcn_mfma_f32_16x16x32_bf16(ah[mt][0], bl0, acc[mt], 0, 0, 0);
                acc[mt] = __builtin_amdgcn_mfma_f32_16x16x32_bf16(ah[mt][1], bl1, acc[mt], 0, 0, 0);
                acc[mt] = __builtin_amdgcn_mfma_f32_16x16x32_bf16(al[mt][0], bh0, acc[mt], 0, 0, 0);
                acc[mt] = __builtin_amdgcn_mfma_f32_16x16x32_bf16(al[mt][1], bh1, acc[mt], 0, 0, 0);
            }
#pragma unroll
            for (int mt = 0; mt < 4; ++mt)
#pragma unroll
                for (int r = 0; r < 4; ++r) {
                    float s = fmaf(-2.f, acc[mt][r], xq[mt][r] + wq);
                    UPD(S1[mt][r], J1[mt][r], S2[mt][r], J2[mt][r], s, n);
                }
        }
    }

    // butterfly top-2 merge across the 16 lanes sharing each token
#pragma unroll
    for (int mt = 0; mt < 4; ++mt)
#pragma unroll
        for (int r = 0; r < 4; ++r) {
            float s1 = S1[mt][r], s2 = S2[mt][r];
            int   j1 = J1[mt][r], j2 = J2[mt][r];
#pragma unroll
            for (int msk = 1; msk < 16; msk <<= 1) {
                float os1 = __shfl_xor(s1, msk, 64); int oj1 = __shfl_xor(j1, msk, 64);
                float os2 = __shfl_xor(s2, msk, 64); int oj2 = __shfl_xor(j2, msk, 64);
                UPD(s1, j1, s2, j2, os1, oj1);
                UPD(s1, j1, s2, j2, os2, oj2);
            }
            S1[mt][r] = s1; S2[mt][r] = s2; J1[mt][r] = j1; J2[mt][r] = j2;
        }

    if (l15 == 0) {
#pragma unroll
        for (int mt = 0; mt < 4; ++mt)
#pragma unroll
            for (int r = 0; r < 4; ++r) {
                int mlocal = wbase + (mt << 4) + (quad << 2) + r;
                out_arg[t0 + mlocal] = (float)J1[mt][r];
                if (S2[mt][r] - S1[mt][r] < GAP_T) {
                    unsigned idx = atomicAdd(flagcnt, 1u);
                    if (idx < 131072u) flaglist[idx] = (unsigned)(t0 + mlocal);
                }
            }
    }
}

// wave-per-4-tokens exact fp32 (+f64 tie) re-decision; fixes out_arg only.
// w float4 loads shared across the 4 tokens (32 KB L2 traffic/token).
__global__ __launch_bounds__(256) void refine_kernel(
    const float* __restrict__ x, const float* __restrict__ w, const float* __restrict__ wsq,
    const unsigned* __restrict__ flagcnt, const unsigned* __restrict__ flaglist,
    float* __restrict__ out_arg)
{
    const unsigned count = min(*flagcnt, 131072u);
    if (count == 0) return;
    const int lane = threadIdx.x & 63;
    const unsigned gw = (blockIdx.x << 2) + (unsigned)(threadIdx.x >> 6);
    const unsigned nw = gridDim.x << 2;
    const unsigned ng4 = (count + 3) >> 2;

    for (unsigned g4 = gw; g4 < ng4; g4 += nw) {
        unsigned base = g4 << 2;
        unsigned tks[4];
        float xd[4], xq[4];
#pragma unroll
        for (int u = 0; u < 4; ++u) {
            unsigned idx = base + (unsigned)u;
            if (idx >= count) idx = count - 1;
            unsigned t = flaglist[idx];
            tks[u] = t;
            xd[u] = x[(t >> 12) * BSTR + lane * 4096 + (t & 4095u)];
            xq[u] = xd[u] * xd[u];
        }
#pragma unroll
        for (int m = 1; m < 64; m <<= 1) {
#pragma unroll
            for (int u = 0; u < 4; ++u) xq[u] += __shfl_xor(xq[u], m, 64);
        }

        float accv[4][8];
#pragma unroll
        for (int u = 0; u < 4; ++u)
#pragma unroll
            for (int k = 0; k < 8; ++k) accv[u][k] = 0.f;

#pragma unroll 4
        for (int d = 0; d < EMB; ++d) {
            float4 wa = *(const float4*)(w + d * NEMB + (lane << 2));
            float4 wb = *(const float4*)(w + d * NEMB + 256 + (lane << 2));
            float wr[8] = {wa.x, wa.y, wa.z, wa.w, wb.x, wb.y, wb.z, wb.w};
#pragma unroll
            for (int u = 0; u < 4; ++u) {
                float xv = __shfl(xd[u], d, 64);
#pragma unroll
                for (int k = 0; k < 8; ++k) accv[u][k] = fmaf(xv, wr[k], accv[u][k]);
            }
        }

#pragma unroll
        for (int u = 0; u < 4; ++u) {
            float S1 = 3.4e38f, S2 = 3.4e38f; int J1 = 0, J2 = 0;
#pragma unroll
            for (int k = 0; k < 8; ++k) {
                int j = (k < 4) ? ((lane << 2) + k) : (256 + (lane << 2) + k - 4);
                float s = (xq[u] - 2.f * accv[u][k]) + wsq[j];
                UPD(S1, J1, S2, J2, s, j);
            }
#pragma unroll
            for (int m = 1; m < 64; m <<= 1) {
                float os1 = __shfl_xor(S1, m, 64); int oj1 = __shfl_xor(J1, m, 64);
                float os2 = __shfl_xor(S2, m, 64); int oj2 = __shfl_xor(J2, m, 64);
                UPD(S1, J1, S2, J2, os1, oj1);
                UPD(S1, J1, S2, J2, os2, oj2);
            }

            int jm = J1;
            if (S2 - S1 < 1e-3f) {
                float w1 = w[lane * NEMB + J1];
                float w2 = w[lane * NEMB + J2];
                double e1 = (double)w1 * (double)w1 - 2.0 * (double)xd[u] * (double)w1;
                double e2 = (double)w2 * (double)w2 - 2.0 * (double)xd[u] * (double)w2;
#pragma unroll
                for (int m = 1; m < 64; m <<= 1) {
                    e1 += __shfl_xor(e1, m, 64);
                    e2 += __shfl_xor(e2, m, 64);
                }
                if (e2 < e1 || (e2 == e1 && J2 < J1)) jm = J2;
            }
            if (lane == 0 && (base + (unsigned)u) < count) out_arg[tks[u]] = (float)jm;
        }
    }
}

// fused: result write + es/cnt accumulation. grid = 65 grp x 16 chunks (1040 blocks).
// grp<64: d=grp. grp==64: counts. LDS accumulate, atomic flush to zeroed outputs.
__global__ __launch_bounds__(256) void finish_kernel(
    const float* __restrict__ x, const float* __restrict__ w, const float* __restrict__ arg,
    float* __restrict__ out_result,
    float* __restrict__ es, float* __restrict__ cnt)
{
    __shared__ float wrow[NEMB];
    __shared__ float acc[NEMB];
    const int tid = threadIdx.x;
    const int grp = blockIdx.x >> 4;     // 0..64
    const int chunk = blockIdx.x & 15;

    acc[tid] = 0.f; acc[tid + 256] = 0.f;
    if (grp < 64) {
        wrow[tid] = w[grp * NEMB + tid];
        wrow[tid + 256] = w[grp * NEMB + tid + 256];
    }
    __syncthreads();

    const int tbase = chunk << 13;       // 8192 tokens per chunk
    if (grp < 64) {
        const int d = grp;
        for (int it = 0; it < 32; it += 4) {
            int jj[4], oo[4];
            float vv[4];
#pragma unroll
            for (int u = 0; u < 4; ++u) {
                int t = tbase + ((it + u) << 8) + tid;
                int o = (t >> 12) * BSTR + d * 4096 + (t & 4095);
                oo[u] = o;
                jj[u] = (int)arg[t];
                vv[u] = x[o];
            }
#pragma unroll
            for (int u = 0; u < 4; ++u) {
                atomicAdd(&acc[jj[u]], vv[u]);           // LDS atomic
                out_result[oo[u]] = wrow[jj[u]];
            }
        }
    } else {
        for (int it = 0; it < 32; it += 4) {
            int jj[4];
#pragma unroll
            for (int u = 0; u < 4; ++u) jj[u] = (int)arg[tbase + ((it + u) << 8) + tid];
#pragma unroll
            for (int u = 0; u < 4; ++u) atomicAdd(&acc[jj[u]], 1.0f);
        }
    }
    __syncthreads();

    float* dst = (grp < 64) ? (es + grp * NEMB) : cnt;
#pragma unroll
    for (int k = 0; k < 2; ++k) {
        int j = tid + (k << 8);
        float v = acc[j];
        if (v != 0.f) atomicAdd(&dst[j], v);
    }
}

// counts accumulated in ncs_io -> new_cluster_size in place; n -> ws_n
__global__ void finalize_cs(const float* __restrict__ cs_in, float* __restrict__ ncs_io,
                            float* __restrict__ ws_n) {
    __shared__ float red[NEMB];
    int j = threadIdx.x;
    float c = ncs_io[j];
    float nidx = (c == 0.f) ? 1.f : c;
    float ncs = DECAYF * cs_in[j] + OMDF * nidx;
    ncs_io[j] = ncs;
    red[j] = ncs;
    __syncthreads();
    for (int s = 256; s > 0; s >>= 1) {
        if (j < s) red[j] += red[j + s];
        __syncthreads();
    }
    if (j == 0) ws_n[0] = red[0];
}

// es accumulated in avg_io -> new_embed_avg in place and new_weight
__global__ void finalize_w(const float* __restrict__ avg_in,
                           const float* __restrict__ ncs, const float* __restrict__ ws_n,
                           float* __restrict__ out_w, float* __restrict__ avg_io) {
    int d = blockIdx.x, j = threadIdx.x;
    int o = d * NEMB + j;
    float n = ws_n[0];
    float ncsj = ncs[j];
    float csj = (ncsj + EPSF) / (n + (float)NEMB * EPSF) * n;
    float esv = avg_io[o];
    float navg = DECAYF * avg_in[o] + OMDF * esv;
    avg_io[o] = navg;
    out_w[o] = navg / csj;
}

extern "C" void kernel_launch(void* const* d_in, const int* in_sizes, int n_in,
                              void* d_out, int out_size, void* d_ws, size_t ws_size,
                              hipStream_t stream) {
    (void)in_sizes; (void)n_in; (void)out_size; (void)ws_size;
    const float* x   = (const float*)d_in[0];
    const float* w   = (const float*)d_in[1];
    const float* cs  = (const float*)d_in[2];
    const float* avg = (const float*)d_in[3];

    float* out = (float*)d_out;
    float* out_result = out;                 // 8388608
    float* out_arg    = out + 8388608;       // 131072
    float* out_w      = out + 8519680;       // 32768
    float* out_ncs    = out + 8552448;       // 512   (counts accumulate here)
    float* out_avg    = out + 8552960;       // 32768 (embed_sum accumulates here)

    char* wsb = (char*)d_ws;
    unsigned short* wh = (unsigned short*)wsb;             // 65536 B
    unsigned short* wl = (unsigned short*)(wsb + 65536);   // 65536 B
    float* wsq      = (float*)(wsb + 131072);              // 2048 B
    float* ws_n     = (float*)(wsb + 133120);              // 4 B
    unsigned* flagcnt = (unsigned*)(wsb + 133376);         // 4 B
    unsigned* flaglist = (unsigned*)(wsb + 133632);        // 524288 B

    hipMemsetAsync(out_ncs, 0, (size_t)33280 * sizeof(float), stream);
    hipMemsetAsync(flagcnt, 0, sizeof(unsigned), stream);
    prep_kernel<<<8, 512, 0, stream>>>(w, wh, wl);
    wsq_kernel<<<1, 512, 0, stream>>>(w, wsq);
    vq_main<<<512, 256, 0, stream>>>(x, wh, wl, wsq, out_arg, flagcnt, flaglist);
    refine_kernel<<<128, 256, 0, stream>>>(x, w, wsq, flagcnt, flaglist, out_arg);
    finish_kernel<<<1040, 256, 0, stream>>>(x, w, out_arg, out_result, out_avg, out_ncs);
    finalize_cs<<<1, 512, 0, stream>>>(cs, out_ncs, ws_n);
    finalize_w<<<64, 512, 0, stream>>>(avg, out_ncs, ws_n, out_w, out_avg);
}

// Round 6
// 235.870 us; speedup vs baseline: 3.2258x; 1.0766x over previous
//
#include <hip/hip_runtime.h>

#define NEMB 512
#define EMB 64
#define BSTR 262144          // 64*4096
#define DECAYF 0.99f
#define OMDF 0.01f
#define EPSF 1e-5f
#define GAP_T 0.012f

typedef __attribute__((ext_vector_type(8))) short bf16x8;
typedef __attribute__((ext_vector_type(4))) float f32x4;

__device__ __forceinline__ unsigned short f2bf(float f) {
    unsigned u = __float_as_uint(f);
    return (unsigned short)((u + 0x7FFFu + ((u >> 16) & 1u)) >> 16);   // RNE
}
__device__ __forceinline__ float bf2f(unsigned short h) {
    return __uint_as_float(((unsigned)h) << 16);
}

// 8 blocks x 512 threads: block b handles d in [8b, 8b+8); vectorized 16B stores
__global__ void prep_kernel(const float* __restrict__ w,
                            unsigned short* __restrict__ wh, unsigned short* __restrict__ wl) {
    int j = threadIdx.x;
    int d0 = blockIdx.x << 3;
    bf16x8 hb, lb;
#pragma unroll
    for (int i = 0; i < 8; ++i) {
        float v = w[(d0 + i) * NEMB + j];
        unsigned short h = f2bf(v);
        hb[i] = (short)h;
        lb[i] = (short)f2bf(v - bf2f(h));
    }
    *(bf16x8*)(wh + j * EMB + d0) = hb;
    *(bf16x8*)(wl + j * EMB + d0) = lb;
}

__global__ void wsq_kernel(const float* __restrict__ w, float* __restrict__ wsq) {
    int j = threadIdx.x;  // 512
    float s = 0.f;
#pragma unroll
    for (int d = 0; d < EMB; ++d) { float v = w[d * NEMB + j]; s = fmaf(v, v, s); }
    wsq[j] = s;
}

#define UPD(S1, J1, S2, J2, s_, j_) do { \
    if (s_ < S1 || (s_ == S1 && j_ < J1)) { S2 = S1; J2 = J1; S1 = s_; J1 = j_; } \
    else if (s_ < S2 || (s_ == S2 && j_ < J2)) { S2 = s_; J2 = j_; } } while (0)

// block = 128 tokens (2 h-rows), 4 waves x 32 tokens. Split-bf16 MFMA distances.
// Exact (v1,j1,v2) tracking, 7 VALU/candidate. 4 blocks/CU.
__global__ __launch_bounds__(256, 4) void vq_main(
    const float* __restrict__ x,
    const unsigned short* __restrict__ wh, const unsigned short* __restrict__ wl,
    const float* __restrict__ wsq,
    float* __restrict__ out_arg,
    unsigned* __restrict__ flagcnt, unsigned* __restrict__ flaglist)
{
    __shared__ __align__(16) float xt[EMB * 128];   // [d][m] 32 KB
    __shared__ float xsq_s[128];
    __shared__ float wsq_s[NEMB];

    const int tid = threadIdx.x;
    const int blk = blockIdx.x;          // 1024
    const int b  = blk >> 5;
    const int h0 = (blk & 31) << 1;      // 2 rows
    const int t0 = b * 4096 + h0 * 64;   // global token base
    const float* xbase = x + b * BSTR + h0 * 64;

#pragma unroll
    for (int it = 0; it < 8; ++it) {
        int idx = tid + (it << 8);       // float4 idx 0..2047
        int d = idx >> 5, q = idx & 31;
        float4 v = *(const float4*)(xbase + d * 4096 + (q << 2));
        *(float4*)(xt + d * 128 + (q << 2)) = v;
    }
    wsq_s[tid] = wsq[tid];
    wsq_s[tid + 256] = wsq[tid + 256];
    __syncthreads();

    if (tid < 128) {
        float s = 0.f;
#pragma unroll
        for (int d = 0; d < EMB; ++d) { float v = xt[d * 128 + tid]; s = fmaf(v, v, s); }
        xsq_s[tid] = s;
    }
    __syncthreads();

    const int lane = tid & 63;
    const int wave = tid >> 6;
    const int l15  = lane & 15;
    const int quad = lane >> 4;
    const int wbase = wave << 5;         // 32 tokens per wave

    // A fragments once (hi/lo), reused across all code chunks
    bf16x8 ah[2][2], al[2][2];
#pragma unroll
    for (int mt = 0; mt < 2; ++mt) {
        int m = wbase + (mt << 4) + l15;
#pragma unroll
        for (int ks = 0; ks < 2; ++ks) {
            int k0 = (ks << 5) + (quad << 3);
            bf16x8 hh, ll;
#pragma unroll
            for (int i = 0; i < 8; ++i) {
                float v = xt[(k0 + i) * 128 + m];
                unsigned short h = f2bf(v);
                hh[i] = (short)h;
                ll[i] = (short)f2bf(v - bf2f(h));
            }
            ah[mt][ks] = hh; al[mt][ks] = ll;
        }
    }

    float xq[2][4];
#pragma unroll
    for (int mt = 0; mt < 2; ++mt)
#pragma unroll
        for (int r = 0; r < 4; ++r)
            xq[mt][r] = xsq_s[wbase + (mt << 4) + (quad << 2) + r];

    float v1[2][4], v2[2][4];
    int   j1[2][4];
#pragma unroll
    for (int mt = 0; mt < 2; ++mt)
#pragma unroll
        for (int r = 0; r < 4; ++r) { v1[mt][r] = 3.4e38f; v2[mt][r] = 3.4e38f; j1[mt][r] = 0; }

    for (int c = 0; c < 8; ++c) {
#pragma unroll
        for (int nt = 0; nt < 4; ++nt) {
            int n = (c << 6) + (nt << 4) + l15;
            const unsigned short* ph = wh + n * EMB;
            const unsigned short* pl = wl + n * EMB;
            bf16x8 bh0 = *(const bf16x8*)(ph + (quad << 3));
            bf16x8 bh1 = *(const bf16x8*)(ph + 32 + (quad << 3));
            bf16x8 bl0 = *(const bf16x8*)(pl + (quad << 3));
            bf16x8 bl1 = *(const bf16x8*)(pl + 32 + (quad << 3));
            float wq = wsq_s[n];

            f32x4 acc[2];
#pragma unroll
            for (int mt = 0; mt < 2; ++mt) acc[mt] = (f32x4){0.f, 0.f, 0.f, 0.f};
#pragma unroll
            for (int mt = 0; mt < 2; ++mt) {
                acc[mt] = __builtin_amdgcn_mfma_f32_16x16x32_bf16(ah[mt][0], bh0, acc[mt], 0, 0, 0);
                acc[mt] = __builtin_amdgcn_mfma_f32_16x16x32_bf16(ah[mt][1], bh1, acc[mt], 0, 0, 0);
                acc[mt] = __builtin_amdgcn_mfma_f32_16x16x32_bf16(ah[mt][0], bl0, acc[mt], 0, 0, 0);
                acc[mt] = __builtin_amdgcn_mfma_f32_16x16x32_bf16(ah[mt][1], bl1, acc[mt], 0, 0, 0);
                acc[mt] = __builtin_amdgcn_mfma_f32_16x16x32_bf16(al[mt][0], bh0, acc[mt], 0, 0, 0);
                acc[mt] = __builtin_amdgcn_mfma_f32_16x16x32_bf16(al[mt][1], bh1, acc[mt], 0, 0, 0);
            }
#pragma unroll
            for (int mt = 0; mt < 2; ++mt)
#pragma unroll
                for (int r = 0; r < 4; ++r) {
                    float s = fmaf(-2.f, acc[mt][r], xq[mt][r] + wq);
                    bool pred = s < v1[mt][r];
                    float mx = fmaxf(s, v1[mt][r]);
                    v1[mt][r] = fminf(s, v1[mt][r]);
                    v2[mt][r] = fminf(v2[mt][r], mx);
                    j1[mt][r] = pred ? n : j1[mt][r];
                }
        }
    }

    // butterfly merge (v1,j1,v2) across the 16 lanes sharing each token
#pragma unroll
    for (int mt = 0; mt < 2; ++mt)
#pragma unroll
        for (int r = 0; r < 4; ++r) {
            float a1 = v1[mt][r], a2 = v2[mt][r];
            int   aj = j1[mt][r];
#pragma unroll
            for (int msk = 1; msk < 16; msk <<= 1) {
                float o1 = __shfl_xor(a1, msk, 64);
                int   oj = __shfl_xor(aj, msk, 64);
                float o2 = __shfl_xor(a2, msk, 64);
                bool take = (o1 < a1) || (o1 == a1 && oj < aj);
                float mx = fmaxf(a1, o1);
                a2 = fminf(fminf(a2, o2), mx);
                a1 = fminf(a1, o1);
                aj = take ? oj : aj;
            }
            v1[mt][r] = a1; v2[mt][r] = a2; j1[mt][r] = aj;
        }

    if (l15 == 0) {
#pragma unroll
        for (int mt = 0; mt < 2; ++mt)
#pragma unroll
            for (int r = 0; r < 4; ++r) {
                int mlocal = wbase + (mt << 4) + (quad << 2) + r;
                out_arg[t0 + mlocal] = (float)j1[mt][r];
                if (v2[mt][r] - v1[mt][r] < GAP_T) {
                    unsigned idx = atomicAdd(flagcnt, 1u);
                    if (idx < 131072u) flaglist[idx] = (unsigned)(t0 + mlocal);
                }
            }
    }
}

// wave-per-4-tokens exact fp32 (+f64 tie) re-decision; fixes out_arg only.
__global__ __launch_bounds__(256) void refine_kernel(
    const float* __restrict__ x, const float* __restrict__ w, const float* __restrict__ wsq,
    const unsigned* __restrict__ flagcnt, const unsigned* __restrict__ flaglist,
    float* __restrict__ out_arg)
{
    const unsigned count = min(*flagcnt, 131072u);
    if (count == 0) return;
    const int lane = threadIdx.x & 63;
    const unsigned gw = (blockIdx.x << 2) + (unsigned)(threadIdx.x >> 6);
    const unsigned nw = gridDim.x << 2;
    const unsigned ng4 = (count + 3) >> 2;

    for (unsigned g4 = gw; g4 < ng4; g4 += nw) {
        unsigned base = g4 << 2;
        unsigned tks[4];
        float xd[4], xq[4];
#pragma unroll
        for (int u = 0; u < 4; ++u) {
            unsigned idx = base + (unsigned)u;
            if (idx >= count) idx = count - 1;
            unsigned t = flaglist[idx];
            tks[u] = t;
            xd[u] = x[(t >> 12) * BSTR + lane * 4096 + (t & 4095u)];
            xq[u] = xd[u] * xd[u];
        }
#pragma unroll
        for (int m = 1; m < 64; m <<= 1) {
#pragma unroll
            for (int u = 0; u < 4; ++u) xq[u] += __shfl_xor(xq[u], m, 64);
        }

        float accv[4][8];
#pragma unroll
        for (int u = 0; u < 4; ++u)
#pragma unroll
            for (int k = 0; k < 8; ++k) accv[u][k] = 0.f;

#pragma unroll 4
        for (int d = 0; d < EMB; ++d) {
            float4 wa = *(const float4*)(w + d * NEMB + (lane << 2));
            float4 wb = *(const float4*)(w + d * NEMB + 256 + (lane << 2));
            float wr[8] = {wa.x, wa.y, wa.z, wa.w, wb.x, wb.y, wb.z, wb.w};
#pragma unroll
            for (int u = 0; u < 4; ++u) {
                float xv = __shfl(xd[u], d, 64);
#pragma unroll
                for (int k = 0; k < 8; ++k) accv[u][k] = fmaf(xv, wr[k], accv[u][k]);
            }
        }

#pragma unroll
        for (int u = 0; u < 4; ++u) {
            float S1 = 3.4e38f, S2 = 3.4e38f; int J1 = 0, J2 = 0;
#pragma unroll
            for (int k = 0; k < 8; ++k) {
                int j = (k < 4) ? ((lane << 2) + k) : (256 + (lane << 2) + k - 4);
                float s = (xq[u] - 2.f * accv[u][k]) + wsq[j];
                UPD(S1, J1, S2, J2, s, j);
            }
#pragma unroll
            for (int m = 1; m < 64; m <<= 1) {
                float os1 = __shfl_xor(S1, m, 64); int oj1 = __shfl_xor(J1, m, 64);
                float os2 = __shfl_xor(S2, m, 64); int oj2 = __shfl_xor(J2, m, 64);
                UPD(S1, J1, S2, J2, os1, oj1);
                UPD(S1, J1, S2, J2, os2, oj2);
            }

            int jm = J1;
            if (S2 - S1 < 1e-3f) {
                float w1 = w[lane * NEMB + J1];
                float w2 = w[lane * NEMB + J2];
                double e1 = (double)w1 * (double)w1 - 2.0 * (double)xd[u] * (double)w1;
                double e2 = (double)w2 * (double)w2 - 2.0 * (double)xd[u] * (double)w2;
#pragma unroll
                for (int m = 1; m < 64; m <<= 1) {
                    e1 += __shfl_xor(e1, m, 64);
                    e2 += __shfl_xor(e2, m, 64);
                }
                if (e2 < e1 || (e2 == e1 && J2 < J1)) jm = J2;
            }
            if (lane == 0 && (base + (unsigned)u) < count) out_arg[tks[u]] = (float)jm;
        }
    }
}

// fused: result write + es/cnt accumulation. grid = 65 grp x 16 chunks (1040 blocks).
// float4-vectorized over 4 consecutive tokens. LDS accumulate, atomic flush.
__global__ __launch_bounds__(256) void finish_kernel(
    const float* __restrict__ x, const float* __restrict__ w, const float* __restrict__ arg,
    float* __restrict__ out_result,
    float* __restrict__ es, float* __restrict__ cnt)
{
    __shared__ float wrow[NEMB];
    __shared__ float acc[NEMB];
    const int tid = threadIdx.x;
    const int grp = blockIdx.x >> 4;     // 0..64
    const int chunk = blockIdx.x & 15;

    acc[tid] = 0.f; acc[tid + 256] = 0.f;
    if (grp < 64) {
        wrow[tid] = w[grp * NEMB + tid];
        wrow[tid + 256] = w[grp * NEMB + tid + 256];
    }
    __syncthreads();

    const int tbase = chunk << 13;       // 8192 tokens per chunk
    if (grp < 64) {
        const int d = grp;
#pragma unroll 2
        for (int it = 0; it < 8; ++it) {
            int t = tbase + (it << 10) + (tid << 2);      // 4 consecutive tokens, same b
            int o = (t >> 12) * BSTR + d * 4096 + (t & 4095);
            float4 a4 = *(const float4*)(arg + t);
            float4 x4 = *(const float4*)(x + o);
            int j0 = (int)a4.x, j1 = (int)a4.y, j2 = (int)a4.z, j3 = (int)a4.w;
            atomicAdd(&acc[j0], x4.x);
            atomicAdd(&acc[j1], x4.y);
            atomicAdd(&acc[j2], x4.z);
            atomicAdd(&acc[j3], x4.w);
            float4 r4 = {wrow[j0], wrow[j1], wrow[j2], wrow[j3]};
            *(float4*)(out_result + o) = r4;
        }
    } else {
#pragma unroll 2
        for (int it = 0; it < 8; ++it) {
            int t = tbase + (it << 10) + (tid << 2);
            float4 a4 = *(const float4*)(arg + t);
            atomicAdd(&acc[(int)a4.x], 1.0f);
            atomicAdd(&acc[(int)a4.y], 1.0f);
            atomicAdd(&acc[(int)a4.z], 1.0f);
            atomicAdd(&acc[(int)a4.w], 1.0f);
        }
    }
    __syncthreads();

    float* dst = (grp < 64) ? (es + grp * NEMB) : cnt;
#pragma unroll
    for (int k = 0; k < 2; ++k) {
        int j = tid + (k << 8);
        float v = acc[j];
        if (v != 0.f) atomicAdd(&dst[j], v);
    }
}

// counts accumulated in ncs_io -> new_cluster_size in place; n -> ws_n
__global__ void finalize_cs(const float* __restrict__ cs_in, float* __restrict__ ncs_io,
                            float* __restrict__ ws_n) {
    __shared__ float red[NEMB];
    int j = threadIdx.x;
    float c = ncs_io[j];
    float nidx = (c == 0.f) ? 1.f : c;
    float ncs = DECAYF * cs_in[j] + OMDF * nidx;
    ncs_io[j] = ncs;
    red[j] = ncs;
    __syncthreads();
    for (int s = 256; s > 0; s >>= 1) {
        if (j < s) red[j] += red[j + s];
        __syncthreads();
    }
    if (j == 0) ws_n[0] = red[0];
}

// es accumulated in avg_io -> new_embed_avg in place and new_weight
__global__ void finalize_w(const float* __restrict__ avg_in,
                           const float* __restrict__ ncs, const float* __restrict__ ws_n,
                           float* __restrict__ out_w, float* __restrict__ avg_io) {
    int d = blockIdx.x, j = threadIdx.x;
    int o = d * NEMB + j;
    float n = ws_n[0];
    float ncsj = ncs[j];
    float csj = (ncsj + EPSF) / (n + (float)NEMB * EPSF) * n;
    float esv = avg_io[o];
    float navg = DECAYF * avg_in[o] + OMDF * esv;
    avg_io[o] = navg;
    out_w[o] = navg / csj;
}

extern "C" void kernel_launch(void* const* d_in, const int* in_sizes, int n_in,
                              void* d_out, int out_size, void* d_ws, size_t ws_size,
                              hipStream_t stream) {
    (void)in_sizes; (void)n_in; (void)out_size; (void)ws_size;
    const float* x   = (const float*)d_in[0];
    const float* w   = (const float*)d_in[1];
    const float* cs  = (const float*)d_in[2];
    const float* avg = (const float*)d_in[3];

    float* out = (float*)d_out;
    float* out_result = out;                 // 8388608
    float* out_arg    = out + 8388608;       // 131072
    float* out_w      = out + 8519680;       // 32768
    float* out_ncs    = out + 8552448;       // 512   (counts accumulate here)
    float* out_avg    = out + 8552960;       // 32768 (embed_sum accumulates here)

    char* wsb = (char*)d_ws;
    unsigned short* wh = (unsigned short*)wsb;             // 65536 B
    unsigned short* wl = (unsigned short*)(wsb + 65536);   // 65536 B
    float* wsq      = (float*)(wsb + 131072);              // 2048 B
    float* ws_n     = (float*)(wsb + 133120);              // 4 B
    unsigned* flagcnt = (unsigned*)(wsb + 133376);         // 4 B
    unsigned* flaglist = (unsigned*)(wsb + 133632);        // 524288 B

    hipMemsetAsync(out_ncs, 0, (size_t)33280 * sizeof(float), stream);
    hipMemsetAsync(flagcnt, 0, sizeof(unsigned), stream);
    prep_kernel<<<8, 512, 0, stream>>>(w, wh, wl);
    wsq_kernel<<<1, 512, 0, stream>>>(w, wsq);
    vq_main<<<1024, 256, 0, stream>>>(x, wh, wl, wsq, out_arg, flagcnt, flaglist);
    refine_kernel<<<128, 256, 0, stream>>>(x, w, wsq, flagcnt, flaglist, out_arg);
    finish_kernel<<<1040, 256, 0, stream>>>(x, w, out_arg, out_result, out_avg, out_ncs);
    finalize_cs<<<1, 512, 0, stream>>>(cs, out_ncs, ws_n);
    finalize_w<<<64, 512, 0, stream>>>(avg, out_ncs, ws_n, out_w, out_avg);
}

// Round 7
// 231.639 us; speedup vs baseline: 3.2847x; 1.0183x over previous
//
#include <hip/hip_runtime.h>

#define NEMB 512
#define EMB 64
#define BSTR 262144          // 64*4096
#define DECAYF 0.99f
#define OMDF 0.01f
#define EPSF 1e-5f
#define GAP_T 0.012f

typedef __attribute__((ext_vector_type(8))) short bf16x8;
typedef __attribute__((ext_vector_type(4))) float f32x4;

__device__ __forceinline__ unsigned short f2bf(float f) {
    unsigned u = __float_as_uint(f);
    return (unsigned short)((u + 0x7FFFu + ((u >> 16) & 1u)) >> 16);   // RNE
}
__device__ __forceinline__ float bf2f(unsigned short h) {
    return __uint_as_float(((unsigned)h) << 16);
}

// 9 blocks x 512 threads.
// blocks 0-7: split w into bf16 hi/lo transposed [n][k], vectorized stores.
// block 8: wsq + zero flagcnt + zero the cnt/es accumulator region (33280 floats).
__global__ void prep_kernel(const float* __restrict__ w,
                            unsigned short* __restrict__ wh, unsigned short* __restrict__ wl,
                            float* __restrict__ wsq, unsigned* __restrict__ flagcnt,
                            float* __restrict__ zero_region) {
    int j = threadIdx.x;
    if (blockIdx.x < 8) {
        int d0 = blockIdx.x << 3;
        bf16x8 hb, lb;
#pragma unroll
        for (int i = 0; i < 8; ++i) {
            float v = w[(d0 + i) * NEMB + j];
            unsigned short h = f2bf(v);
            hb[i] = (short)h;
            lb[i] = (short)f2bf(v - bf2f(h));
        }
        *(bf16x8*)(wh + j * EMB + d0) = hb;
        *(bf16x8*)(wl + j * EMB + d0) = lb;
    } else {
        float s = 0.f;
#pragma unroll
        for (int d = 0; d < EMB; ++d) { float v = w[d * NEMB + j]; s = fmaf(v, v, s); }
        wsq[j] = s;
        if (j == 0) *flagcnt = 0u;
#pragma unroll
        for (int k = j; k < 33280; k += 512) zero_region[k] = 0.f;
    }
}

#define UPD(S1, J1, S2, J2, s_, j_) do { \
    if (s_ < S1 || (s_ == S1 && j_ < J1)) { S2 = S1; J2 = J1; S1 = s_; J1 = j_; } \
    else if (s_ < S2 || (s_ == S2 && j_ < J2)) { S2 = s_; J2 = j_; } } while (0)

// block = 128 tokens (2 h-rows), 4 waves x 32 tokens. Split-bf16 MFMA distances.
// Register double-buffered B-fragments: iteration i+1's loads issued before
// iteration i's MFMAs consume their data (vmcnt(4)-style pipeline, no barriers).
__global__ __launch_bounds__(256, 4) void vq_main(
    const float* __restrict__ x,
    const unsigned short* __restrict__ wh, const unsigned short* __restrict__ wl,
    const float* __restrict__ wsq,
    float* __restrict__ out_arg,
    unsigned* __restrict__ flagcnt, unsigned* __restrict__ flaglist)
{
    __shared__ __align__(16) float xt[EMB * 128];   // [d][m] 32 KB
    __shared__ float xsq_s[128];
    __shared__ float wsq_s[NEMB];

    const int tid = threadIdx.x;
    const int blk = blockIdx.x;          // 1024
    const int b  = blk >> 5;
    const int h0 = (blk & 31) << 1;      // 2 rows
    const int t0 = b * 4096 + h0 * 64;   // global token base
    const float* xbase = x + b * BSTR + h0 * 64;

#pragma unroll
    for (int it = 0; it < 8; ++it) {
        int idx = tid + (it << 8);       // float4 idx 0..2047
        int d = idx >> 5, q = idx & 31;
        float4 v = *(const float4*)(xbase + d * 4096 + (q << 2));
        *(float4*)(xt + d * 128 + (q << 2)) = v;
    }
    wsq_s[tid] = wsq[tid];
    wsq_s[tid + 256] = wsq[tid + 256];
    __syncthreads();

    if (tid < 128) {
        float s = 0.f;
#pragma unroll
        for (int d = 0; d < EMB; ++d) { float v = xt[d * 128 + tid]; s = fmaf(v, v, s); }
        xsq_s[tid] = s;
    }
    __syncthreads();

    const int lane = tid & 63;
    const int wave = tid >> 6;
    const int l15  = lane & 15;
    const int quad = lane >> 4;
    const int wbase = wave << 5;         // 32 tokens per wave

    // A fragments once (hi/lo), reused across all code chunks
    bf16x8 ah[2][2], al[2][2];
#pragma unroll
    for (int mt = 0; mt < 2; ++mt) {
        int m = wbase + (mt << 4) + l15;
#pragma unroll
        for (int ks = 0; ks < 2; ++ks) {
            int k0 = (ks << 5) + (quad << 3);
            bf16x8 hh, ll;
#pragma unroll
            for (int i = 0; i < 8; ++i) {
                float v = xt[(k0 + i) * 128 + m];
                unsigned short h = f2bf(v);
                hh[i] = (short)h;
                ll[i] = (short)f2bf(v - bf2f(h));
            }
            ah[mt][ks] = hh; al[mt][ks] = ll;
        }
    }

    float xq[2][4];
#pragma unroll
    for (int mt = 0; mt < 2; ++mt)
#pragma unroll
        for (int r = 0; r < 4; ++r)
            xq[mt][r] = xsq_s[wbase + (mt << 4) + (quad << 2) + r];

    float v1[2][4], v2[2][4];
    int   j1[2][4];
#pragma unroll
    for (int mt = 0; mt < 2; ++mt)
#pragma unroll
        for (int r = 0; r < 4; ++r) { v1[mt][r] = 3.4e38f; v2[mt][r] = 3.4e38f; j1[mt][r] = 0; }

    const int qoff = quad << 3;
    // prologue: load iteration 0's B fragments (n = l15)
    bf16x8 cb0, cb1, cb2, cb3;
    {
        const unsigned short* ph = wh + l15 * EMB + qoff;
        const unsigned short* pl = wl + l15 * EMB + qoff;
        cb0 = *(const bf16x8*)(ph);
        cb1 = *(const bf16x8*)(ph + 32);
        cb2 = *(const bf16x8*)(pl);
        cb3 = *(const bf16x8*)(pl + 32);
    }
    float wq_c = wsq_s[l15];

#pragma unroll 2
    for (int it = 0; it < 32; ++it) {
        const int n = (it << 4) + l15;
        const int nn = (n + 16) & 511;   // wraps on last iter; result discarded
        // issue next iteration's loads first (stay in flight over the MFMAs)
        bf16x8 nb0, nb1, nb2, nb3;
        {
            const unsigned short* ph = wh + nn * EMB + qoff;
            const unsigned short* pl = wl + nn * EMB + qoff;
            nb0 = *(const bf16x8*)(ph);
            nb1 = *(const bf16x8*)(ph + 32);
            nb2 = *(const bf16x8*)(pl);
            nb3 = *(const bf16x8*)(pl + 32);
        }
        float wq_n = wsq_s[nn];

        f32x4 acc0 = (f32x4){0.f, 0.f, 0.f, 0.f};
        f32x4 acc1 = (f32x4){0.f, 0.f, 0.f, 0.f};
        acc0 = __builtin_amdgcn_mfma_f32_16x16x32_bf16(ah[0][0], cb0, acc0, 0, 0, 0);
        acc1 = __builtin_amdgcn_mfma_f32_16x16x32_bf16(ah[1][0], cb0, acc1, 0, 0, 0);
        acc0 = __builtin_amdgcn_mfma_f32_16x16x32_bf16(ah[0][1], cb1, acc0, 0, 0, 0);
        acc1 = __builtin_amdgcn_mfma_f32_16x16x32_bf16(ah[1][1], cb1, acc1, 0, 0, 0);
        acc0 = __builtin_amdgcn_mfma_f32_16x16x32_bf16(ah[0][0], cb2, acc0, 0, 0, 0);
        acc1 = __builtin_amdgcn_mfma_f32_16x16x32_bf16(ah[1][0], cb2, acc1, 0, 0, 0);
        acc0 = __builtin_amdgcn_mfma_f32_16x16x32_bf16(ah[0][1], cb3, acc0, 0, 0, 0);
        acc1 = __builtin_amdgcn_mfma_f32_16x16x32_bf16(ah[1][1], cb3, acc1, 0, 0, 0);
        acc0 = __builtin_amdgcn_mfma_f32_16x16x32_bf16(al[0][0], cb0, acc0, 0, 0, 0);
        acc1 = __builtin_amdgcn_mfma_f32_16x16x32_bf16(al[1][0], cb0, acc1, 0, 0, 0);
        acc0 = __builtin_amdgcn_mfma_f32_16x16x32_bf16(al[0][1], cb1, acc0, 0, 0, 0);
        acc1 = __builtin_amdgcn_mfma_f32_16x16x32_bf16(al[1][1], cb1, acc1, 0, 0, 0);

#pragma unroll
        for (int r = 0; r < 4; ++r) {
            float s0 = fmaf(-2.f, acc0[r], xq[0][r] + wq_c);
            bool p0 = s0 < v1[0][r];
            float mx0 = fmaxf(s0, v1[0][r]);
            v1[0][r] = fminf(s0, v1[0][r]);
            v2[0][r] = fminf(v2[0][r], mx0);
            j1[0][r] = p0 ? n : j1[0][r];

            float s1 = fmaf(-2.f, acc1[r], xq[1][r] + wq_c);
            bool p1 = s1 < v1[1][r];
            float mx1 = fmaxf(s1, v1[1][r]);
            v1[1][r] = fminf(s1, v1[1][r]);
            v2[1][r] = fminf(v2[1][r], mx1);
            j1[1][r] = p1 ? n : j1[1][r];
        }

        cb0 = nb0; cb1 = nb1; cb2 = nb2; cb3 = nb3; wq_c = wq_n;
    }

    // butterfly merge (v1,j1,v2) across the 16 lanes sharing each token
#pragma unroll
    for (int mt = 0; mt < 2; ++mt)
#pragma unroll
        for (int r = 0; r < 4; ++r) {
            float a1 = v1[mt][r], a2 = v2[mt][r];
            int   aj = j1[mt][r];
#pragma unroll
            for (int msk = 1; msk < 16; msk <<= 1) {
                float o1 = __shfl_xor(a1, msk, 64);
                int   oj = __shfl_xor(aj, msk, 64);
                float o2 = __shfl_xor(a2, msk, 64);
                bool take = (o1 < a1) || (o1 == a1 && oj < aj);
                float mx = fmaxf(a1, o1);
                a2 = fminf(fminf(a2, o2), mx);
                a1 = fminf(a1, o1);
                aj = take ? oj : aj;
            }
            v1[mt][r] = a1; v2[mt][r] = a2; j1[mt][r] = aj;
        }

    if (l15 == 0) {
#pragma unroll
        for (int mt = 0; mt < 2; ++mt)
#pragma unroll
            for (int r = 0; r < 4; ++r) {
                int mlocal = wbase + (mt << 4) + (quad << 2) + r;
                out_arg[t0 + mlocal] = (float)j1[mt][r];
                if (v2[mt][r] - v1[mt][r] < GAP_T) {
                    unsigned idx = atomicAdd(flagcnt, 1u);
                    if (idx < 131072u) flaglist[idx] = (unsigned)(t0 + mlocal);
                }
            }
    }
}

// wave-per-4-tokens exact fp32 (+f64 tie) re-decision; fixes out_arg only.
__global__ __launch_bounds__(256) void refine_kernel(
    const float* __restrict__ x, const float* __restrict__ w, const float* __restrict__ wsq,
    const unsigned* __restrict__ flagcnt, const unsigned* __restrict__ flaglist,
    float* __restrict__ out_arg)
{
    const unsigned count = min(*flagcnt, 131072u);
    if (count == 0) return;
    const int lane = threadIdx.x & 63;
    const unsigned gw = (blockIdx.x << 2) + (unsigned)(threadIdx.x >> 6);
    const unsigned nw = gridDim.x << 2;
    const unsigned ng4 = (count + 3) >> 2;

    for (unsigned g4 = gw; g4 < ng4; g4 += nw) {
        unsigned base = g4 << 2;
        unsigned tks[4];
        float xd[4], xq[4];
#pragma unroll
        for (int u = 0; u < 4; ++u) {
            unsigned idx = base + (unsigned)u;
            if (idx >= count) idx = count - 1;
            unsigned t = flaglist[idx];
            tks[u] = t;
            xd[u] = x[(t >> 12) * BSTR + lane * 4096 + (t & 4095u)];
            xq[u] = xd[u] * xd[u];
        }
#pragma unroll
        for (int m = 1; m < 64; m <<= 1) {
#pragma unroll
            for (int u = 0; u < 4; ++u) xq[u] += __shfl_xor(xq[u], m, 64);
        }

        float accv[4][8];
#pragma unroll
        for (int u = 0; u < 4; ++u)
#pragma unroll
            for (int k = 0; k < 8; ++k) accv[u][k] = 0.f;

#pragma unroll 4
        for (int d = 0; d < EMB; ++d) {
            float4 wa = *(const float4*)(w + d * NEMB + (lane << 2));
            float4 wb = *(const float4*)(w + d * NEMB + 256 + (lane << 2));
            float wr[8] = {wa.x, wa.y, wa.z, wa.w, wb.x, wb.y, wb.z, wb.w};
#pragma unroll
            for (int u = 0; u < 4; ++u) {
                float xv = __shfl(xd[u], d, 64);
#pragma unroll
                for (int k = 0; k < 8; ++k) accv[u][k] = fmaf(xv, wr[k], accv[u][k]);
            }
        }

#pragma unroll
        for (int u = 0; u < 4; ++u) {
            float S1 = 3.4e38f, S2 = 3.4e38f; int J1 = 0, J2 = 0;
#pragma unroll
            for (int k = 0; k < 8; ++k) {
                int j = (k < 4) ? ((lane << 2) + k) : (256 + (lane << 2) + k - 4);
                float s = (xq[u] - 2.f * accv[u][k]) + wsq[j];
                UPD(S1, J1, S2, J2, s, j);
            }
#pragma unroll
            for (int m = 1; m < 64; m <<= 1) {
                float os1 = __shfl_xor(S1, m, 64); int oj1 = __shfl_xor(J1, m, 64);
                float os2 = __shfl_xor(S2, m, 64); int oj2 = __shfl_xor(J2, m, 64);
                UPD(S1, J1, S2, J2, os1, oj1);
                UPD(S1, J1, S2, J2, os2, oj2);
            }

            int jm = J1;
            if (S2 - S1 < 1e-3f) {
                float w1 = w[lane * NEMB + J1];
                float w2 = w[lane * NEMB + J2];
                double e1 = (double)w1 * (double)w1 - 2.0 * (double)xd[u] * (double)w1;
                double e2 = (double)w2 * (double)w2 - 2.0 * (double)xd[u] * (double)w2;
#pragma unroll
                for (int m = 1; m < 64; m <<= 1) {
                    e1 += __shfl_xor(e1, m, 64);
                    e2 += __shfl_xor(e2, m, 64);
                }
                if (e2 < e1 || (e2 == e1 && J2 < J1)) jm = J2;
            }
            if (lane == 0 && (base + (unsigned)u) < count) out_arg[tks[u]] = (float)jm;
        }
    }
}

// fused: result write + es/cnt accumulation. grid = 65 grp x 16 chunks (1040 blocks).
// float4-vectorized over 4 consecutive tokens. LDS accumulate, atomic flush.
__global__ __launch_bounds__(256) void finish_kernel(
    const float* __restrict__ x, const float* __restrict__ w, const float* __restrict__ arg,
    float* __restrict__ out_result,
    float* __restrict__ es, float* __restrict__ cnt)
{
    __shared__ float wrow[NEMB];
    __shared__ float acc[NEMB];
    const int tid = threadIdx.x;
    const int grp = blockIdx.x >> 4;     // 0..64
    const int chunk = blockIdx.x & 15;

    acc[tid] = 0.f; acc[tid + 256] = 0.f;
    if (grp < 64) {
        wrow[tid] = w[grp * NEMB + tid];
        wrow[tid + 256] = w[grp * NEMB + tid + 256];
    }
    __syncthreads();

    const int tbase = chunk << 13;       // 8192 tokens per chunk
    if (grp < 64) {
        const int d = grp;
#pragma unroll 2
        for (int it = 0; it < 8; ++it) {
            int t = tbase + (it << 10) + (tid << 2);      // 4 consecutive tokens, same b
            int o = (t >> 12) * BSTR + d * 4096 + (t & 4095);
            float4 a4 = *(const float4*)(arg + t);
            float4 x4 = *(const float4*)(x + o);
            int j0 = (int)a4.x, j1 = (int)a4.y, j2 = (int)a4.z, j3 = (int)a4.w;
            atomicAdd(&acc[j0], x4.x);
            atomicAdd(&acc[j1], x4.y);
            atomicAdd(&acc[j2], x4.z);
            atomicAdd(&acc[j3], x4.w);
            float4 r4 = {wrow[j0], wrow[j1], wrow[j2], wrow[j3]};
            *(float4*)(out_result + o) = r4;
        }
    } else {
#pragma unroll 2
        for (int it = 0; it < 8; ++it) {
            int t = tbase + (it << 10) + (tid << 2);
            float4 a4 = *(const float4*)(arg + t);
            atomicAdd(&acc[(int)a4.x], 1.0f);
            atomicAdd(&acc[(int)a4.y], 1.0f);
            atomicAdd(&acc[(int)a4.z], 1.0f);
            atomicAdd(&acc[(int)a4.w], 1.0f);
        }
    }
    __syncthreads();

    float* dst = (grp < 64) ? (es + grp * NEMB) : cnt;
#pragma unroll
    for (int k = 0; k < 2; ++k) {
        int j = tid + (k << 8);
        float v = acc[j];
        if (v != 0.f) atomicAdd(&dst[j], v);
    }
}

// counts accumulated in ncs_io -> new_cluster_size in place; n -> ws_n
__global__ void finalize_cs(const float* __restrict__ cs_in, float* __restrict__ ncs_io,
                            float* __restrict__ ws_n) {
    __shared__ float red[NEMB];
    int j = threadIdx.x;
    float c = ncs_io[j];
    float nidx = (c == 0.f) ? 1.f : c;
    float ncs = DECAYF * cs_in[j] + OMDF * nidx;
    ncs_io[j] = ncs;
    red[j] = ncs;
    __syncthreads();
    for (int s = 256; s > 0; s >>= 1) {
        if (j < s) red[j] += red[j + s];
        __syncthreads();
    }
    if (j == 0) ws_n[0] = red[0];
}

// es accumulated in avg_io -> new_embed_avg in place and new_weight
__global__ void finalize_w(const float* __restrict__ avg_in,
                           const float* __restrict__ ncs, const float* __restrict__ ws_n,
                           float* __restrict__ out_w, float* __restrict__ avg_io) {
    int d = blockIdx.x, j = threadIdx.x;
    int o = d * NEMB + j;
    float n = ws_n[0];
    float ncsj = ncs[j];
    float csj = (ncsj + EPSF) / (n + (float)NEMB * EPSF) * n;
    float esv = avg_io[o];
    float navg = DECAYF * avg_in[o] + OMDF * esv;
    avg_io[o] = navg;
    out_w[o] = navg / csj;
}

extern "C" void kernel_launch(void* const* d_in, const int* in_sizes, int n_in,
                              void* d_out, int out_size, void* d_ws, size_t ws_size,
                              hipStream_t stream) {
    (void)in_sizes; (void)n_in; (void)out_size; (void)ws_size;
    const float* x   = (const float*)d_in[0];
    const float* w   = (const float*)d_in[1];
    const float* cs  = (const float*)d_in[2];
    const float* avg = (const float*)d_in[3];

    float* out = (float*)d_out;
    float* out_result = out;                 // 8388608
    float* out_arg    = out + 8388608;       // 131072
    float* out_w      = out + 8519680;       // 32768
    float* out_ncs    = out + 8552448;       // 512   (counts accumulate here)
    float* out_avg    = out + 8552960;       // 32768 (embed_sum accumulates here)

    char* wsb = (char*)d_ws;
    unsigned short* wh = (unsigned short*)wsb;             // 65536 B
    unsigned short* wl = (unsigned short*)(wsb + 65536);   // 65536 B
    float* wsq      = (float*)(wsb + 131072);              // 2048 B
    float* ws_n     = (float*)(wsb + 133120);              // 4 B
    unsigned* flagcnt = (unsigned*)(wsb + 133376);         // 4 B
    unsigned* flaglist = (unsigned*)(wsb + 133632);        // 524288 B

    prep_kernel<<<9, 512, 0, stream>>>(w, wh, wl, wsq, flagcnt, out_ncs);
    vq_main<<<1024, 256, 0, stream>>>(x, wh, wl, wsq, out_arg, flagcnt, flaglist);
    refine_kernel<<<128, 256, 0, stream>>>(x, w, wsq, flagcnt, flaglist, out_arg);
    finish_kernel<<<1040, 256, 0, stream>>>(x, w, out_arg, out_result, out_avg, out_ncs);
    finalize_cs<<<1, 512, 0, stream>>>(cs, out_ncs, ws_n);
    finalize_w<<<64, 512, 0, stream>>>(avg, out_ncs, ws_n, out_w, out_avg);
}